// Round 9
// baseline (980.160 us; speedup 1.0000x reference)
//
#include <hip/hip_runtime.h>
#include <math.h>

// Dims: N=128, C=128, T=64, V=25, S=3, R=32; TV=1600, CTV=204800.
// qk: [n][192r][1600tv] bf16. G/H: [np][s][tv][128o] bf16 (linear in (tv, o)).
// attS_bf: [n][32v][96k] bf16 (k=s*25+u, pads zeroed). attT_bf: [n][64q][192k] (k=s*64+t).
// pre: [np][1600tv][128o] bf16 = BN(att-conv), residual+lrelu fused into cbr stage.

typedef __attribute__((ext_vector_type(8))) short short8v;
typedef __attribute__((ext_vector_type(4))) float f32x4;

__device__ __forceinline__ ushort f2bf(float f) {
    uint b = __float_as_uint(f);
    uint r = b + 0x7fffu + ((b >> 16) & 1u);
    return (ushort)(r >> 16);
}
__device__ __forceinline__ float bf2f(ushort h) {
    return __uint_as_float(((uint)h) << 16);
}

// -------- weight prep (bf16 copies) --------
__global__ __launch_bounds__(256) void wt_prep(
    const float* __restrict__ Wo_s, const float* __restrict__ Wf_s,
    const float* __restrict__ Wo_t, const float* __restrict__ Wf_t,
    const float* __restrict__ Wqk_s, const float* __restrict__ Wqk_t,
    ushort* __restrict__ W16)
{
    int idx = blockIdx.x * 256 + threadIdx.x;
    if (idx >= 180224) return;
    float v;
    if (idx < 49152) {
        int s = idx / 16384, rem = idx % 16384, o = rem / 128, c = rem % 128;
        v = Wo_s[o * 384 + s * 128 + c];
    } else if (idx < 65536) {
        v = Wf_s[idx - 49152];
    } else if (idx < 114688) {
        int i = idx - 65536, s = i / 16384, rem = i % 16384, o = rem / 128, c = rem % 128;
        v = Wo_t[o * 384 + s * 128 + c];
    } else if (idx < 131072) {
        v = Wf_t[idx - 114688];
    } else if (idx < 155648) {
        v = Wqk_s[idx - 131072];
    } else {
        v = Wqk_t[idx - 155648];
    }
    W16[idx] = f2bf(v);
}

// -------- qk_pe (MFMA): qk[n][192r][1600tv] --------
__global__ __launch_bounds__(256) void qk_pe_mfma(
    const float* __restrict__ src, const ushort* __restrict__ Wbf,
    const float* __restrict__ bias, ushort* __restrict__ out, int pos_is_t)
{
    __shared__ __align__(16) ushort xT[160 * 136];
    __shared__ __align__(16) ushort exch[192 * 24];
    const int n = blockIdx.y, tvb = blockIdx.x * 160;
    const float* sn = src + (size_t)n * 204800;
    // stage: 8 tv4 x 8 cp per wave -> reads 128B-coalesced per c-row, LDS ~4-way max
    for (int i = threadIdx.x; i < 2560; i += 256) {
        int tv4 = (i & 7) + (i >> 9) * 8;   // 0..39
        int cp  = (i >> 3) & 63;            // c-pair 0..63
        float4 a = *(const float4*)(sn + (2 * cp) * 1600 + tvb + tv4 * 4);
        float4 b = *(const float4*)(sn + (2 * cp + 1) * 1600 + tvb + tv4 * 4);
        float dv = __expf(-0.14391156831212787f * (float)cp);
        float av[4] = { a.x, a.y, a.z, a.w };
        float bv[4] = { b.x, b.y, b.z, b.w };
#pragma unroll
        for (int e = 0; e < 4; e++) {
            int tv = tvb + tv4 * 4 + e;
            int tt = tv / 25;
            float pos = pos_is_t ? (float)tt : (float)(tv - tt * 25);
            float ang = pos * dv;
            uint p = (uint)f2bf(av[e] + __sinf(ang)) | ((uint)f2bf(bv[e] + __cosf(ang)) << 16);
            ((uint*)xT)[(tv4 * 4 + e) * 68 + cp] = p;
        }
    }
    __syncthreads();
    const int lane = threadIdx.x & 63, wave = threadIdx.x >> 6;
    const int l15 = lane & 15, kg = lane >> 4;
    const int rb = wave * 48;
    short8v wf[3][4];
#pragma unroll
    for (int nt = 0; nt < 3; nt++)
#pragma unroll
        for (int k = 0; k < 4; k++)
            wf[nt][k] = *(const short8v*)&Wbf[(rb + nt * 16 + l15) * 128 + k * 32 + kg * 8];
    float bsv[3];
#pragma unroll
    for (int nt = 0; nt < 3; nt++) bsv[nt] = bias[rb + nt * 16 + l15];
    ushort* on = out + (size_t)n * 307200;
    for (int mt = 0; mt < 10; mt++) {
        short8v af[4];
#pragma unroll
        for (int k = 0; k < 4; k++)
            af[k] = *(short8v*)&xT[(mt * 16 + l15) * 136 + k * 32 + kg * 8];
        f32x4 accs[3];
#pragma unroll
        for (int nt = 0; nt < 3; nt++) {
            f32x4 acc = {0.f, 0.f, 0.f, 0.f};
#pragma unroll
            for (int k = 0; k < 4; k++)
                acc = __builtin_amdgcn_mfma_f32_16x16x32_bf16(af[k], wf[nt][k], acc, 0, 0, 0);
            accs[nt] = acc;
        }
        __syncthreads();   // prior store-loop reads of exch complete
#pragma unroll
        for (int nt = 0; nt < 3; nt++) {
            uint2 pk;
            pk.x = (uint)f2bf(accs[nt][0] + bsv[nt]) | ((uint)f2bf(accs[nt][1] + bsv[nt]) << 16);
            pk.y = (uint)f2bf(accs[nt][2] + bsv[nt]) | ((uint)f2bf(accs[nt][3] + bsv[nt]) << 16);
            *(uint2*)&exch[(rb + nt * 16 + l15) * 24 + kg * 4] = pk;
        }
        __syncthreads();
        for (int i = threadIdx.x; i < 384; i += 256) {
            int r = i >> 1, hh = i & 1;
            *(uint4*)(on + (size_t)r * 1600 + tvb + mt * 16 + hh * 8) =
                *(const uint4*)&exch[r * 24 + hh * 8];
        }
    }
}

// -------- att_s (MFMA) -> attS_bf[n][32v][96k] bf16, k=s*25+u, pads zeroed --------
__global__ __launch_bounds__(256) void att_s_mfma(
    const ushort* __restrict__ qk, const float* __restrict__ alphas,
    const float* __restrict__ att0, ushort* __restrict__ attS_bf)
{
    __shared__ __align__(16) ushort Qs[32 * 520];
    __shared__ __align__(16) ushort Ks[32 * 520];
    const int s = blockIdx.x, n = blockIdx.y;
    const ushort* qb = qk + (size_t)n * 307200 + (size_t)(s * 32) * 1600;
    const ushort* kb = qb + 96 * 1600;
    for (int i = threadIdx.x; i < 3072; i += 256) {
        int v = i / 96, k = i - v * 96;
        if (v >= 25 || k >= 75) attS_bf[(size_t)n * 3072 + i] = 0;
    }
    const int lane = threadIdx.x & 63, wave = threadIdx.x >> 6;
    const int l15 = lane & 15, kg = lane >> 4;
    const int mt = wave >> 1, nt = wave & 1;
    f32x4 acc = {0.f, 0.f, 0.f, 0.f};
    for (int rc = 0; rc < 4; rc++) {
        __syncthreads();
        for (int i = threadIdx.x; i < 6400; i += 256) {
            int rl = i / 800, j = i - rl * 800;
            uint uq = *(const uint*)(qb + (rc * 8 + rl) * 1600 + j * 2);
            uint uk = *(const uint*)(kb + (rc * 8 + rl) * 1600 + j * 2);
            int tv = j * 2;
            int t0 = tv / 25, u0 = tv - t0 * 25;
            int t1 = (tv + 1) / 25, u1 = (tv + 1) - t1 * 25;
            Qs[u0 * 520 + rl * 64 + t0] = (ushort)(uq & 0xffffu);
            Qs[u1 * 520 + rl * 64 + t1] = (ushort)(uq >> 16);
            Ks[u0 * 520 + rl * 64 + t0] = (ushort)(uk & 0xffffu);
            Ks[u1 * 520 + rl * 64 + t1] = (ushort)(uk >> 16);
        }
        __syncthreads();
#pragma unroll
        for (int ks = 0; ks < 16; ks++) {
            short8v a = *(const short8v*)&Qs[(mt * 16 + l15) * 520 + ks * 32 + kg * 8];
            short8v b = *(const short8v*)&Ks[(nt * 16 + l15) * 520 + ks * 32 + kg * 8];
            acc = __builtin_amdgcn_mfma_f32_16x16x32_bf16(a, b, acc, 0, 0, 0);
        }
    }
    float alpha = alphas[s];
#pragma unroll
    for (int rr = 0; rr < 4; rr++) {
        int u = mt * 16 + kg * 4 + rr, v = nt * 16 + l15;
        if (u < 25 && v < 25)
            attS_bf[(size_t)n * 3072 + v * 96 + s * 25 + u] =
                f2bf(tanhf(acc[rr] * (1.0f / 2048.0f)) * alpha + att0[s * 625 + u * 25 + v]);
    }
}

// -------- att_t (MFMA) -> attT_bf[n][64q][192k] bf16, k=s*64+t --------
__global__ __launch_bounds__(256) void att_t_mfma(
    const ushort* __restrict__ qk, const float* __restrict__ alphat,
    const float* __restrict__ att0, ushort* __restrict__ attT_bf)
{
    __shared__ __align__(16) ushort Qt[8 * 64 * 40];
    __shared__ __align__(16) ushort Kt[8 * 64 * 40];
    const int s = blockIdx.x, n = blockIdx.y;
    const ushort* qb = qk + (size_t)n * 307200 + (size_t)(s * 32) * 1600;
    const ushort* kb = qb + 96 * 1600;
    for (int i = threadIdx.x; i < 10240; i += 256) {
        ((uint*)Qt)[i] = 0u;
        ((uint*)Kt)[i] = 0u;
    }
    const int lane = threadIdx.x & 63, wave = threadIdx.x >> 6;
    const int l15 = lane & 15, kg = lane >> 4;
    const int mt = wave;
    f32x4 acc[4];
#pragma unroll
    for (int i = 0; i < 4; i++) acc[i] = (f32x4){0.f, 0.f, 0.f, 0.f};
    for (int rc = 0; rc < 4; rc++) {
        __syncthreads();
        for (int i = threadIdx.x; i < 6400; i += 256) {
            int rl = i / 800, j = i - rl * 800;
            uint uq = *(const uint*)(qb + (rc * 8 + rl) * 1600 + j * 2);
            uint uk = *(const uint*)(kb + (rc * 8 + rl) * 1600 + j * 2);
            int tv = j * 2;
            int t0 = tv / 25, v0 = tv - t0 * 25;
            int t1 = (tv + 1) / 25, v1 = (tv + 1) - t1 * 25;
            Qt[(rl * 64 + t0) * 40 + v0] = (ushort)(uq & 0xffffu);
            Qt[(rl * 64 + t1) * 40 + v1] = (ushort)(uq >> 16);
            Kt[(rl * 64 + t0) * 40 + v0] = (ushort)(uk & 0xffffu);
            Kt[(rl * 64 + t1) * 40 + v1] = (ushort)(uk >> 16);
        }
        __syncthreads();
#pragma unroll
        for (int rl = 0; rl < 8; rl++) {
            short8v a = *(const short8v*)&Qt[(rl * 64 + mt * 16 + l15) * 40 + kg * 8];
#pragma unroll
            for (int nq = 0; nq < 4; nq++) {
                short8v b = *(const short8v*)&Kt[(rl * 64 + nq * 16 + l15) * 40 + kg * 8];
                acc[nq] = __builtin_amdgcn_mfma_f32_16x16x32_bf16(a, b, acc[nq], 0, 0, 0);
            }
        }
    }
    float alpha = alphat[s];
#pragma unroll
    for (int nq = 0; nq < 4; nq++) {
        int q = nq * 16 + l15;
        ushort w4[4];
#pragma unroll
        for (int rr = 0; rr < 4; rr++) {
            int t = mt * 16 + kg * 4 + rr;
            w4[rr] = f2bf(tanhf(acc[nq][rr] * (1.0f / 800.0f)) * alpha +
                          att0[s * 4096 + t * 64 + q]);
        }
        uint2 pk;
        pk.x = (uint)w4[0] | ((uint)w4[1] << 16);
        pk.y = (uint)w4[2] | ((uint)w4[3] << 16);
        *(uint2*)(attT_bf + (size_t)n * 12288 + q * 192 + s * 64 + mt * 16 + kg * 4) = pk;
    }
}

// ------- t1 (MFMA): G[np][s][tv][128o] bf16 = sum_c Wbf[s][o][c] * src[c][tv] -------
__global__ __launch_bounds__(256) void t1_mfma(
    const float* __restrict__ src, const ushort* __restrict__ Wbf,
    ushort* __restrict__ G)
{
    __shared__ __align__(16) ushort xT[160 * 136];
    __shared__ __align__(16) ushort exch[2][16 * 136];
    const int np = blockIdx.y, tvb = blockIdx.x * 160;
    const float* sn = src + (size_t)np * 204800;
    for (int i = threadIdx.x; i < 2560; i += 256) {
        int tv4 = (i & 7) + (i >> 9) * 8;
        int cp  = (i >> 3) & 63;
        float4 a = *(const float4*)(sn + (2 * cp) * 1600 + tvb + tv4 * 4);
        float4 b = *(const float4*)(sn + (2 * cp + 1) * 1600 + tvb + tv4 * 4);
        float av[4] = { a.x, a.y, a.z, a.w };
        float bv[4] = { b.x, b.y, b.z, b.w };
#pragma unroll
        for (int e = 0; e < 4; e++) {
            uint p = (uint)f2bf(av[e]) | ((uint)f2bf(bv[e]) << 16);
            ((uint*)xT)[(tv4 * 4 + e) * 68 + cp] = p;
        }
    }
    __syncthreads();
    const int lane = threadIdx.x & 63, wave = threadIdx.x >> 6;
    const int l15 = lane & 15, kg = lane >> 4;
    const int o_base = wave * 32;
    int buf = 0;
    for (int s = 0; s < 3; s++) {
        short8v bfr[2][4];
#pragma unroll
        for (int nt = 0; nt < 2; nt++)
#pragma unroll
            for (int k = 0; k < 4; k++)
                bfr[nt][k] = *(const short8v*)&Wbf[s * 16384 +
                              (o_base + nt * 16 + l15) * 128 + k * 32 + kg * 8];
        ushort* Gs = G + (size_t)(np * 3 + s) * 64 * 3200;
        for (int mt = 0; mt < 10; mt++) {
            short8v af[4];
#pragma unroll
            for (int k = 0; k < 4; k++)
                af[k] = *(short8v*)&xT[(mt * 16 + l15) * 136 + k * 32 + kg * 8];
            f32x4 acc0 = {0.f, 0.f, 0.f, 0.f};
            f32x4 acc1 = {0.f, 0.f, 0.f, 0.f};
#pragma unroll
            for (int k = 0; k < 4; k++) {
                acc0 = __builtin_amdgcn_mfma_f32_16x16x32_bf16(af[k], bfr[0][k], acc0, 0, 0, 0);
                acc1 = __builtin_amdgcn_mfma_f32_16x16x32_bf16(af[k], bfr[1][k], acc1, 0, 0, 0);
            }
#pragma unroll
            for (int r = 0; r < 4; r++) {
                exch[buf][(kg * 4 + r) * 136 + o_base + l15]      = f2bf(acc0[r]);
                exch[buf][(kg * 4 + r) * 136 + o_base + 16 + l15] = f2bf(acc1[r]);
            }
            __syncthreads();
            // drain: 16 rows x 128 ushorts = 1024 uints (FIX: was 512)
            for (int i = threadIdx.x; i < 1024; i += 256) {
                int rl = i >> 6, col = i & 63;
                ((uint*)(Gs + (size_t)(tvb + mt * 16 + rl) * 128))[col] =
                    ((const uint*)&exch[buf][rl * 136])[col];
            }
            buf ^= 1;
        }
    }
}

// ------- s2 (MFMA): pre[tv][128o] = BN( sum_{su} attS_bf[v][su] * H[su][(t,o)] ) -------
__global__ __launch_bounds__(256) void s2_mfma(
    const ushort* __restrict__ H, const ushort* __restrict__ attS,
    const float* __restrict__ bnp, const float* __restrict__ bo,
    ushort* __restrict__ pre)
{
    __shared__ __align__(16) ushort Bt[256 * 128]; // [n=tl*128+o][k swz], stride 128
    __shared__ float sc_l[128], of_l[128];
    const int np = blockIdx.y, t0 = blockIdx.x * 2;
    if (threadIdx.x < 128) {
        int o = threadIdx.x;
        float sc = bnp[o] * rsqrtf(bnp[384 + o] + 1e-5f);
        sc_l[o] = sc;
        of_l[o] = (bo[o] - bnp[256 + o]) * sc + bnp[128 + o];
    }
    const int lane = threadIdx.x & 63, wave = threadIdx.x >> 6;
    const int l15 = lane & 15, kg = lane >> 4;
    const ushort* An = attS + (size_t)np * 3072;
    short8v a[2][3];
#pragma unroll
    for (int mt = 0; mt < 2; mt++)
#pragma unroll
        for (int ks = 0; ks < 3; ks++)
            a[mt][ks] = *(const short8v*)(An + (mt * 16 + l15) * 96 + ks * 32 + kg * 8);
    for (int i = threadIdx.x; i < 5376; i += 256) {
        int n = i / 21, k = 75 + i % 21;
        Bt[n * 128 + (((k >> 3) ^ ((n >> 1) & 7)) << 3) + (k & 7)] = 0;
    }
    const ushort* Hq = H + (size_t)np * 192 * 3200;
    for (int i = threadIdx.x; i < 9600; i += 256) {
        int op = i & 63, row = i >> 6;
        int s = row / 50, r2 = row - s * 50, tl = r2 / 25, u = r2 - tl * 25;
        uint w = *(const uint*)(Hq + (s * 64 + t0 + tl) * 3200 + u * 128 + op * 2);
        int k = s * 25 + u;
        int n0 = tl * 128 + op * 2;
        int base = n0 * 128 + (((k >> 3) ^ ((n0 >> 1) & 7)) << 3) + (k & 7);
        Bt[base]       = (ushort)(w & 0xffffu);
        Bt[base + 128] = (ushort)(w >> 16);
    }
    __syncthreads();
    f32x4 acc[2][4];
#pragma unroll
    for (int mt = 0; mt < 2; mt++)
#pragma unroll
        for (int jj = 0; jj < 4; jj++) acc[mt][jj] = (f32x4){0.f, 0.f, 0.f, 0.f};
    const int jb = wave * 4;
#pragma unroll
    for (int ks = 0; ks < 3; ks++) {
        short8v b[4];
#pragma unroll
        for (int jj = 0; jj < 4; jj++) {
            int n = (jb + jj) * 16 + l15;
            b[jj] = *(const short8v*)&Bt[n * 128 + ((((ks * 4 + kg) ^ ((n >> 1) & 7))) << 3)];
        }
#pragma unroll
        for (int mt = 0; mt < 2; mt++)
#pragma unroll
            for (int jj = 0; jj < 4; jj++)
                acc[mt][jj] = __builtin_amdgcn_mfma_f32_16x16x32_bf16(a[mt][ks], b[jj], acc[mt][jj], 0, 0, 0);
    }
    ushort* pq = pre + (size_t)np * 204800;
#pragma unroll
    for (int mt = 0; mt < 2; mt++)
#pragma unroll
        for (int jj = 0; jj < 4; jj++) {
            int n = (jb + jj) * 16 + l15;
            int tl = n >> 7, o = n & 127;
            float sc = sc_l[o], of = of_l[o];
#pragma unroll
            for (int rr = 0; rr < 4; rr++) {
                int v = mt * 16 + kg * 4 + rr;
                if (v < 25)
                    pq[((t0 + tl) * 25 + v) * 128 + o] = f2bf(acc[mt][jj][rr] * sc + of);
            }
        }
}

// ------- t2 (MFMA): pre[(q*25+v)][128o] = BN( sum_{st} attT_bf[q][st] * G[st][v][o] ) -------
__global__ __launch_bounds__(256) void t2_mfma(
    const ushort* __restrict__ G, const ushort* __restrict__ attT,
    const float* __restrict__ bnp, const float* __restrict__ bo,
    ushort* __restrict__ pre)
{
    __shared__ __align__(16) ushort Bt[128 * 256]; // [o][k swz], stride 256
    __shared__ float sc_l[128], of_l[128];
    const int v = blockIdx.x, np = blockIdx.y;
    if (threadIdx.x < 128) {
        int o = threadIdx.x;
        float sc = bnp[o] * rsqrtf(bnp[384 + o] + 1e-5f);
        sc_l[o] = sc;
        of_l[o] = (bo[o] - bnp[256 + o]) * sc + bnp[128 + o];
    }
    const int lane = threadIdx.x & 63, wave = threadIdx.x >> 6;
    const int l15 = lane & 15, kg = lane >> 4;
    const ushort* An = attT + (size_t)np * 12288;
    short8v a[4][6];
#pragma unroll
    for (int mt = 0; mt < 4; mt++)
#pragma unroll
        for (int ks = 0; ks < 6; ks++)
            a[mt][ks] = *(const short8v*)(An + (mt * 16 + l15) * 192 + ks * 32 + kg * 8);
    const ushort* Gq = G + (size_t)np * 192 * 3200 + v * 128;
    for (int i = threadIdx.x; i < 12288; i += 256) {
        int op = i & 63, st = i >> 6;
        uint w = *(const uint*)(Gq + st * 3200 + op * 2);
        int o0 = op * 2;
        int base = o0 * 256 + (((st >> 3) ^ ((o0 >> 1) & 7)) << 3) + (st & 7);
        Bt[base]       = (ushort)(w & 0xffffu);
        Bt[base + 256] = (ushort)(w >> 16);
    }
    __syncthreads();
    f32x4 acc[4][2];
#pragma unroll
    for (int mt = 0; mt < 4; mt++)
#pragma unroll
        for (int jj = 0; jj < 2; jj++) acc[mt][jj] = (f32x4){0.f, 0.f, 0.f, 0.f};
    const int jb = wave * 2;
#pragma unroll
    for (int ks = 0; ks < 6; ks++) {
        short8v b[2];
#pragma unroll
        for (int jj = 0; jj < 2; jj++) {
            int o = (jb + jj) * 16 + l15;
            b[jj] = *(const short8v*)&Bt[o * 256 + ((((ks * 4 + kg) ^ ((o >> 1) & 7))) << 3)];
        }
#pragma unroll
        for (int mt = 0; mt < 4; mt++)
#pragma unroll
            for (int jj = 0; jj < 2; jj++)
                acc[mt][jj] = __builtin_amdgcn_mfma_f32_16x16x32_bf16(a[mt][ks], b[jj], acc[mt][jj], 0, 0, 0);
    }
    ushort* pq = pre + (size_t)np * 204800;
#pragma unroll
    for (int mt = 0; mt < 4; mt++)
#pragma unroll
        for (int jj = 0; jj < 2; jj++) {
            int o = (jb + jj) * 16 + l15;
            float sc = sc_l[o], of = of_l[o];
#pragma unroll
            for (int rr = 0; rr < 4; rr++) {
                int q = mt * 16 + kg * 4 + rr;
                pq[(q * 25 + v) * 128 + o] = f2bf(acc[mt][jj][rr] * sc + of);
            }
        }
}

// ------- cbr (MFMA): out = lrelu(res + BN2(Wf @ lrelu(res + pre) + b)) -------
__global__ __launch_bounds__(256) void cbr_mfma(
    const ushort* __restrict__ pre, const float* res,
    const ushort* __restrict__ Wbf, const float* __restrict__ bias,
    const float* __restrict__ bnp, float* outp)
{
    __shared__ __align__(16) ushort xT[160 * 136];
    __shared__ float sc_l[128], of_l[128];
    const int np = blockIdx.y, tvb = blockIdx.x * 160;
    if (threadIdx.x < 128) {
        int o = threadIdx.x;
        float sc = bnp[o] * rsqrtf(bnp[384 + o] + 1e-5f);
        sc_l[o] = sc;
        of_l[o] = (bias[o] - bnp[256 + o]) * sc + bnp[128 + o];
    }
    const ushort* pp = pre + (size_t)np * 204800 + (size_t)tvb * 128;
    for (int i = threadIdx.x; i < 10240; i += 256) {
        int tl = i >> 6, cp = i & 63;
        ((uint*)xT)[tl * 68 + cp] = *(const uint*)(pp + tl * 128 + cp * 2);
    }
    __syncthreads();
    const float* rq = res + (size_t)np * 204800;
    for (int i = threadIdx.x; i < 5120; i += 256) {
        int tv = i % 160, cq = i / 160, c = cq * 4;
        uint2 w = *(uint2*)&xT[tv * 136 + c];
        float h0 = rq[(size_t)(c + 0) * 1600 + tvb + tv] + bf2f((ushort)(w.x & 0xffffu));
        float h1 = rq[(size_t)(c + 1) * 1600 + tvb + tv] + bf2f((ushort)(w.x >> 16));
        float h2 = rq[(size_t)(c + 2) * 1600 + tvb + tv] + bf2f((ushort)(w.y & 0xffffu));
        float h3 = rq[(size_t)(c + 3) * 1600 + tvb + tv] + bf2f((ushort)(w.y >> 16));
        h0 = h0 > 0.f ? h0 : 0.1f * h0;
        h1 = h1 > 0.f ? h1 : 0.1f * h1;
        h2 = h2 > 0.f ? h2 : 0.1f * h2;
        h3 = h3 > 0.f ? h3 : 0.1f * h3;
        w.x = (uint)f2bf(h0) | ((uint)f2bf(h1) << 16);
        w.y = (uint)f2bf(h2) | ((uint)f2bf(h3) << 16);
        *(uint2*)&xT[tv * 136 + c] = w;
    }
    __syncthreads();
    const int lane = threadIdx.x & 63, wave = threadIdx.x >> 6;
    const int l15 = lane & 15, kg = lane >> 4;
    const int ob = wave * 32;
    short8v af[2][4];
#pragma unroll
    for (int mt = 0; mt < 2; mt++)
#pragma unroll
        for (int k = 0; k < 4; k++)
            af[mt][k] = *(const short8v*)&Wbf[(ob + mt * 16 + l15) * 128 + k * 32 + kg * 8];
    for (int nt = 0; nt < 10; nt++) {
        short8v bfg[4];
#pragma unroll
        for (int k = 0; k < 4; k++)
            bfg[k] = *(short8v*)&xT[(nt * 16 + l15) * 136 + k * 32 + kg * 8];
        f32x4 acc0 = {0.f, 0.f, 0.f, 0.f};
        f32x4 acc1 = {0.f, 0.f, 0.f, 0.f};
#pragma unroll
        for (int k = 0; k < 4; k++) {
            acc0 = __builtin_amdgcn_mfma_f32_16x16x32_bf16(af[0][k], bfg[k], acc0, 0, 0, 0);
            acc1 = __builtin_amdgcn_mfma_f32_16x16x32_bf16(af[1][k], bfg[k], acc1, 0, 0, 0);
        }
        int tv = tvb + nt * 16 + l15;
#pragma unroll
        for (int rr = 0; rr < 4; rr++) {
            {
                int o = ob + kg * 4 + rr;
                size_t idx = (size_t)np * 204800 + (size_t)o * 1600 + tv;
                float h = acc0[rr] * sc_l[o] + of_l[o] + res[idx];
                outp[idx] = h > 0.f ? h : 0.1f * h;
            }
            {
                int o = ob + 16 + kg * 4 + rr;
                size_t idx = (size_t)np * 204800 + (size_t)o * 1600 + tv;
                float h = acc1[rr] * sc_l[o] + of_l[o] + res[idx];
                outp[idx] = h > 0.f ? h : 0.1f * h;
            }
        }
    }
}

extern "C" void kernel_launch(void* const* d_in, const int* in_sizes, int n_in,
                              void* d_out, int out_size, void* d_ws, size_t ws_size,
                              hipStream_t stream)
{
    (void)in_sizes; (void)n_in; (void)out_size; (void)ws_size;
    const float* x      = (const float*)d_in[0];
    const float* Wqk_s  = (const float*)d_in[1];
    const float* bqk_s  = (const float*)d_in[2];
    const float* alphas = (const float*)d_in[3];
    const float* att0s  = (const float*)d_in[4];
    const float* Wo_s   = (const float*)d_in[5];
    const float* bo_s   = (const float*)d_in[6];
    const float* bn_o_s = (const float*)d_in[7];
    const float* Wf_s   = (const float*)d_in[8];
    const float* bf_s   = (const float*)d_in[9];
    const float* bn_f_s = (const float*)d_in[10];
    const float* Wqk_t  = (const float*)d_in[11];
    const float* bqk_t  = (const float*)d_in[12];
    const float* alphat = (const float*)d_in[13];
    const float* att0t  = (const float*)d_in[14];
    const float* Wo_t   = (const float*)d_in[15];
    const float* bo_t   = (const float*)d_in[16];
    const float* bn_o_t = (const float*)d_in[17];
    const float* Wf_t   = (const float*)d_in[18];
    const float* bf_t   = (const float*)d_in[19];
    const float* bn_f_t = (const float*)d_in[20];

    float* out = (float*)d_out;
    const size_t CTV = 204800;
    ushort* qk      = (ushort*)d_ws;
    ushort* Gbuf    = (ushort*)d_ws;
    ushort* pre     = (ushort*)((char*)d_ws + 39321600);
    ushort* attS_bf = (ushort*)((char*)d_ws + 78643200);
    ushort* attT_bf = (ushort*)((char*)d_ws + 79603200);
    ushort* W16     = (ushort*)((char*)d_ws + 85894656);
    const ushort* WoS_bf  = W16;
    const ushort* WfS_bf  = W16 + 49152;
    const ushort* WoT_bf  = W16 + 65536;
    const ushort* WfT_bf  = W16 + 114688;
    const ushort* WqkS_bf = W16 + 131072;
    const ushort* WqkT_bf = W16 + 155648;

    wt_prep<<<704, 256, 0, stream>>>(Wo_s, Wf_s, Wo_t, Wf_t, Wqk_s, Wqk_t, W16);

    dim3 gqk(10, 128), gatt(3, 128), gt1(10, 32), gs2(32, 32), gt2(25, 32), gcbr(10, 32);

    // ---- spatial ----
    qk_pe_mfma<<<gqk, 256, 0, stream>>>(x, WqkS_bf, bqk_s, qk, 0);
    att_s_mfma<<<gatt, 256, 0, stream>>>(qk, alphas, att0s, attS_bf);
    for (int h = 0; h < 4; h++) {
        size_t n0 = (size_t)h * 32;
        t1_mfma<<<gt1, 256, 0, stream>>>(x + n0 * CTV, WoS_bf, Gbuf);
        s2_mfma<<<gs2, 256, 0, stream>>>(Gbuf, attS_bf + n0 * 3072, bn_o_s, bo_s, pre);
        cbr_mfma<<<gcbr, 256, 0, stream>>>(pre, x + n0 * CTV, WfS_bf, bf_s, bn_f_s,
                                           out + n0 * CTV);
    }

    // ---- temporal ----
    qk_pe_mfma<<<gqk, 256, 0, stream>>>(out, WqkT_bf, bqk_t, qk, 1);
    att_t_mfma<<<gatt, 256, 0, stream>>>(qk, alphat, att0t, attT_bf);
    for (int h = 0; h < 4; h++) {
        size_t n0 = (size_t)h * 32;
        t1_mfma<<<gt1, 256, 0, stream>>>(out + n0 * CTV, WoT_bf, Gbuf);
        t2_mfma<<<gt2, 256, 0, stream>>>(Gbuf, attT_bf + n0 * 12288, bn_o_t, bo_t, pre);
        cbr_mfma<<<gcbr, 256, 0, stream>>>(pre, out + n0 * CTV, WfT_bf, bf_t, bn_f_t,
                                           out + n0 * CTV);
    }
}

// Round 10
// 727.224 us; speedup vs baseline: 1.3478x; 1.3478x over previous
//
#include <hip/hip_runtime.h>
#include <math.h>

// Dims: N=128, C=128, T=64, V=25, S=3, R=32; TV=1600, CTV=204800.
// qk: [n][192r][1600tv] bf16. G: [np][s][tv][128o] bf16 (temporal only).
// attS_bf: [n][32v][96k] bf16, k=s*32+u (pads zero). attT_bf: [n][64q][192k] (k=s*64+t).
// Spatial post-att: single fused kernel (t1+s2+cbr in LDS). Temporal: quartered t1/t2/cbr.

typedef __attribute__((ext_vector_type(8))) short short8v;
typedef __attribute__((ext_vector_type(4))) float f32x4;

__device__ __forceinline__ ushort f2bf(float f) {
    uint b = __float_as_uint(f);
    uint r = b + 0x7fffu + ((b >> 16) & 1u);
    return (ushort)(r >> 16);
}
__device__ __forceinline__ float bf2f(ushort h) {
    return __uint_as_float(((uint)h) << 16);
}

// -------- weight prep (bf16 copies) --------
__global__ __launch_bounds__(256) void wt_prep(
    const float* __restrict__ Wo_s, const float* __restrict__ Wf_s,
    const float* __restrict__ Wo_t, const float* __restrict__ Wf_t,
    const float* __restrict__ Wqk_s, const float* __restrict__ Wqk_t,
    ushort* __restrict__ W16)
{
    int idx = blockIdx.x * 256 + threadIdx.x;
    if (idx >= 180224) return;
    float v;
    if (idx < 49152) {
        int s = idx / 16384, rem = idx % 16384, o = rem / 128, c = rem % 128;
        v = Wo_s[o * 384 + s * 128 + c];
    } else if (idx < 65536) {
        v = Wf_s[idx - 49152];
    } else if (idx < 114688) {
        int i = idx - 65536, s = i / 16384, rem = i % 16384, o = rem / 128, c = rem % 128;
        v = Wo_t[o * 384 + s * 128 + c];
    } else if (idx < 131072) {
        v = Wf_t[idx - 114688];
    } else if (idx < 155648) {
        v = Wqk_s[idx - 131072];
    } else {
        v = Wqk_t[idx - 155648];
    }
    W16[idx] = f2bf(v);
}

// -------- qk_pe (MFMA): qk[n][192r][1600tv] --------
__global__ __launch_bounds__(256) void qk_pe_mfma(
    const float* __restrict__ src, const ushort* __restrict__ Wbf,
    const float* __restrict__ bias, ushort* __restrict__ out, int pos_is_t)
{
    __shared__ __align__(16) ushort xT[160 * 136];
    __shared__ __align__(16) ushort exch[192 * 24];
    const int n = blockIdx.y, tvb = blockIdx.x * 160;
    const float* sn = src + (size_t)n * 204800;
    for (int i = threadIdx.x; i < 2560; i += 256) {
        int tv4 = (i & 7) + (i >> 9) * 8;   // 0..39
        int cp  = (i >> 3) & 63;            // c-pair 0..63
        float4 a = *(const float4*)(sn + (2 * cp) * 1600 + tvb + tv4 * 4);
        float4 b = *(const float4*)(sn + (2 * cp + 1) * 1600 + tvb + tv4 * 4);
        float dv = __expf(-0.14391156831212787f * (float)cp);
        float av[4] = { a.x, a.y, a.z, a.w };
        float bv[4] = { b.x, b.y, b.z, b.w };
#pragma unroll
        for (int e = 0; e < 4; e++) {
            int tv = tvb + tv4 * 4 + e;
            int tt = tv / 25;
            float pos = pos_is_t ? (float)tt : (float)(tv - tt * 25);
            float ang = pos * dv;
            uint p = (uint)f2bf(av[e] + __sinf(ang)) | ((uint)f2bf(bv[e] + __cosf(ang)) << 16);
            ((uint*)xT)[(tv4 * 4 + e) * 68 + cp] = p;
        }
    }
    __syncthreads();
    const int lane = threadIdx.x & 63, wave = threadIdx.x >> 6;
    const int l15 = lane & 15, kg = lane >> 4;
    const int rb = wave * 48;
    short8v wf[3][4];
#pragma unroll
    for (int nt = 0; nt < 3; nt++)
#pragma unroll
        for (int k = 0; k < 4; k++)
            wf[nt][k] = *(const short8v*)&Wbf[(rb + nt * 16 + l15) * 128 + k * 32 + kg * 8];
    float bsv[3];
#pragma unroll
    for (int nt = 0; nt < 3; nt++) bsv[nt] = bias[rb + nt * 16 + l15];
    ushort* on = out + (size_t)n * 307200;
    for (int mt = 0; mt < 10; mt++) {
        short8v af[4];
#pragma unroll
        for (int k = 0; k < 4; k++)
            af[k] = *(short8v*)&xT[(mt * 16 + l15) * 136 + k * 32 + kg * 8];
        f32x4 accs[3];
#pragma unroll
        for (int nt = 0; nt < 3; nt++) {
            f32x4 acc = {0.f, 0.f, 0.f, 0.f};
#pragma unroll
            for (int k = 0; k < 4; k++)
                acc = __builtin_amdgcn_mfma_f32_16x16x32_bf16(af[k], wf[nt][k], acc, 0, 0, 0);
            accs[nt] = acc;
        }
        __syncthreads();
#pragma unroll
        for (int nt = 0; nt < 3; nt++) {
            uint2 pk;
            pk.x = (uint)f2bf(accs[nt][0] + bsv[nt]) | ((uint)f2bf(accs[nt][1] + bsv[nt]) << 16);
            pk.y = (uint)f2bf(accs[nt][2] + bsv[nt]) | ((uint)f2bf(accs[nt][3] + bsv[nt]) << 16);
            *(uint2*)&exch[(rb + nt * 16 + l15) * 24 + kg * 4] = pk;
        }
        __syncthreads();
        for (int i = threadIdx.x; i < 384; i += 256) {
            int r = i >> 1, hh = i & 1;
            *(uint4*)(on + (size_t)r * 1600 + tvb + mt * 16 + hh * 8) =
                *(const uint4*)&exch[r * 24 + hh * 8];
        }
    }
}

// -------- att_s (MFMA) -> attS_bf[n][32v][96k] bf16, k=s*32+u, pads zeroed --------
__global__ __launch_bounds__(256) void att_s_mfma(
    const ushort* __restrict__ qk, const float* __restrict__ alphas,
    const float* __restrict__ att0, ushort* __restrict__ attS_bf)
{
    __shared__ __align__(16) ushort Qs[32 * 520];
    __shared__ __align__(16) ushort Ks[32 * 520];
    const int s = blockIdx.x, n = blockIdx.y;
    const ushort* qb = qk + (size_t)n * 307200 + (size_t)(s * 32) * 1600;
    const ushort* kb = qb + 96 * 1600;
    // zero invalid region (benign same-value race across the 3 s-blocks of this n)
    for (int i = threadIdx.x; i < 3072; i += 256) {
        int v = i / 96, k = i - v * 96;
        if (v >= 25 || (k & 31) >= 25) attS_bf[(size_t)n * 3072 + i] = 0;
    }
    const int lane = threadIdx.x & 63, wave = threadIdx.x >> 6;
    const int l15 = lane & 15, kg = lane >> 4;
    const int mt = wave >> 1, nt = wave & 1;
    f32x4 acc = {0.f, 0.f, 0.f, 0.f};
    for (int rc = 0; rc < 4; rc++) {
        __syncthreads();
        for (int i = threadIdx.x; i < 6400; i += 256) {
            int rl = i / 800, j = i - rl * 800;
            uint uq = *(const uint*)(qb + (rc * 8 + rl) * 1600 + j * 2);
            uint uk = *(const uint*)(kb + (rc * 8 + rl) * 1600 + j * 2);
            int tv = j * 2;
            int t0 = tv / 25, u0 = tv - t0 * 25;
            int t1 = (tv + 1) / 25, u1 = (tv + 1) - t1 * 25;
            Qs[u0 * 520 + rl * 64 + t0] = (ushort)(uq & 0xffffu);
            Qs[u1 * 520 + rl * 64 + t1] = (ushort)(uq >> 16);
            Ks[u0 * 520 + rl * 64 + t0] = (ushort)(uk & 0xffffu);
            Ks[u1 * 520 + rl * 64 + t1] = (ushort)(uk >> 16);
        }
        __syncthreads();
#pragma unroll
        for (int ks = 0; ks < 16; ks++) {
            short8v a = *(const short8v*)&Qs[(mt * 16 + l15) * 520 + ks * 32 + kg * 8];
            short8v b = *(const short8v*)&Ks[(nt * 16 + l15) * 520 + ks * 32 + kg * 8];
            acc = __builtin_amdgcn_mfma_f32_16x16x32_bf16(a, b, acc, 0, 0, 0);
        }
    }
    float alpha = alphas[s];
#pragma unroll
    for (int rr = 0; rr < 4; rr++) {
        int u = mt * 16 + kg * 4 + rr, v = nt * 16 + l15;
        if (u < 25 && v < 25)
            attS_bf[(size_t)n * 3072 + v * 96 + s * 32 + u] =
                f2bf(tanhf(acc[rr] * (1.0f / 2048.0f)) * alpha + att0[s * 625 + u * 25 + v]);
    }
}

// -------- att_t (MFMA) -> attT_bf[n][64q][192k] bf16, k=s*64+t --------
__global__ __launch_bounds__(256) void att_t_mfma(
    const ushort* __restrict__ qk, const float* __restrict__ alphat,
    const float* __restrict__ att0, ushort* __restrict__ attT_bf)
{
    __shared__ __align__(16) ushort Qt[8 * 64 * 40];
    __shared__ __align__(16) ushort Kt[8 * 64 * 40];
    const int s = blockIdx.x, n = blockIdx.y;
    const ushort* qb = qk + (size_t)n * 307200 + (size_t)(s * 32) * 1600;
    const ushort* kb = qb + 96 * 1600;
    for (int i = threadIdx.x; i < 10240; i += 256) {
        ((uint*)Qt)[i] = 0u;
        ((uint*)Kt)[i] = 0u;
    }
    const int lane = threadIdx.x & 63, wave = threadIdx.x >> 6;
    const int l15 = lane & 15, kg = lane >> 4;
    const int mt = wave;
    f32x4 acc[4];
#pragma unroll
    for (int i = 0; i < 4; i++) acc[i] = (f32x4){0.f, 0.f, 0.f, 0.f};
    for (int rc = 0; rc < 4; rc++) {
        __syncthreads();
        for (int i = threadIdx.x; i < 6400; i += 256) {
            int rl = i / 800, j = i - rl * 800;
            uint uq = *(const uint*)(qb + (rc * 8 + rl) * 1600 + j * 2);
            uint uk = *(const uint*)(kb + (rc * 8 + rl) * 1600 + j * 2);
            int tv = j * 2;
            int t0 = tv / 25, v0 = tv - t0 * 25;
            int t1 = (tv + 1) / 25, v1 = (tv + 1) - t1 * 25;
            Qt[(rl * 64 + t0) * 40 + v0] = (ushort)(uq & 0xffffu);
            Qt[(rl * 64 + t1) * 40 + v1] = (ushort)(uq >> 16);
            Kt[(rl * 64 + t0) * 40 + v0] = (ushort)(uk & 0xffffu);
            Kt[(rl * 64 + t1) * 40 + v1] = (ushort)(uk >> 16);
        }
        __syncthreads();
#pragma unroll
        for (int rl = 0; rl < 8; rl++) {
            short8v a = *(const short8v*)&Qt[(rl * 64 + mt * 16 + l15) * 40 + kg * 8];
#pragma unroll
            for (int nq = 0; nq < 4; nq++) {
                short8v b = *(const short8v*)&Kt[(rl * 64 + nq * 16 + l15) * 40 + kg * 8];
                acc[nq] = __builtin_amdgcn_mfma_f32_16x16x32_bf16(a, b, acc[nq], 0, 0, 0);
            }
        }
    }
    float alpha = alphat[s];
#pragma unroll
    for (int nq = 0; nq < 4; nq++) {
        int q = nq * 16 + l15;
        ushort w4[4];
#pragma unroll
        for (int rr = 0; rr < 4; rr++) {
            int t = mt * 16 + kg * 4 + rr;
            w4[rr] = f2bf(tanhf(acc[nq][rr] * (1.0f / 800.0f)) * alpha +
                          att0[s * 4096 + t * 64 + q]);
        }
        uint2 pk;
        pk.x = (uint)w4[0] | ((uint)w4[1] << 16);
        pk.y = (uint)w4[2] | ((uint)w4[3] << 16);
        *(uint2*)(attT_bf + (size_t)n * 12288 + q * 192 + s * 64 + mt * 16 + kg * 4) = pk;
    }
}

// ------- s_fused: whole spatial post-attention, one block per (n, 2t) -------
// y1 = lrelu(x + BN1(sum_{s,u} attS[s,u,v] * H[o,s,t,u])), H = Wo_s @ x
// out = lrelu(x + BN2(Wf_s @ y1))
__global__ __launch_bounds__(256) void s_fused(
    const float* __restrict__ x, const ushort* __restrict__ Wo /*[3][128o][128c]*/,
    const ushort* __restrict__ attS /*[n][32v][96k]*/, const ushort* __restrict__ Wf,
    const float* __restrict__ bnO, const float* __restrict__ boO,
    const float* __restrict__ bnF, const float* __restrict__ bfF,
    float* __restrict__ outp)
{
    __shared__ __align__(16) ushort xT[64 * 136];   // [tv_local][c] (rows 50..63 unused)
    __shared__ __align__(16) ushort Bt[256 * 32];   // [n'=(tl,o)][k=u swz] per s
    __shared__ __align__(16) ushort y1T[64 * 136];
    __shared__ float sc1[128], of1[128], sc2[128], of2[128];
    const int n = blockIdx.y, tb = blockIdx.x;
    const int tvg0 = tb * 50;
    if (threadIdx.x < 128) {
        int o = threadIdx.x;
        float s1 = bnO[o] * rsqrtf(bnO[384 + o] + 1e-5f);
        sc1[o] = s1; of1[o] = (boO[o] - bnO[256 + o]) * s1 + bnO[128 + o];
    } else {
        int o = threadIdx.x - 128;
        float s2 = bnF[o] * rsqrtf(bnF[384 + o] + 1e-5f);
        sc2[o] = s2; of2[o] = (bfF[o] - bnF[256 + o]) * s2 + bnF[128 + o];
    }
    // zero Bt pad cols u=25..31 (stay zero: t1 writes only u<25)
    for (int i = threadIdx.x; i < 1792; i += 256) {
        int nr = i / 7, k = 25 + i % 7;
        Bt[nr * 32 + (((k >> 3) ^ ((nr >> 1) & 3)) << 3) + (k & 7)] = 0;
    }
    const float* xn = x + (size_t)n * 204800;
    for (int i = threadIdx.x; i < 3200; i += 256) {
        int c = i / 25, j2 = i - c * 25;
        float2 v2 = *(const float2*)(xn + c * 1600 + tvg0 + j2 * 2);
        xT[(j2 * 2) * 136 + c]     = f2bf(v2.x);
        xT[(j2 * 2 + 1) * 136 + c] = f2bf(v2.y);
    }
    __syncthreads();
    const int lane = threadIdx.x & 63, wave = threadIdx.x >> 6;
    const int l15 = lane & 15, kg = lane >> 4;
    const int ob = wave * 32, jb = wave * 4;
    f32x4 accS[2][4];
#pragma unroll
    for (int mt = 0; mt < 2; mt++)
#pragma unroll
        for (int jj = 0; jj < 4; jj++) accS[mt][jj] = (f32x4){0.f, 0.f, 0.f, 0.f};
    const ushort* An = attS + (size_t)n * 3072;
    for (int s = 0; s < 3; s++) {
        // H (t1-part): A = xT (M=tv), B = Wo_s (N=o, wave's 32)
        short8v bW[2][4];
#pragma unroll
        for (int ot = 0; ot < 2; ot++)
#pragma unroll
            for (int k = 0; k < 4; k++)
                bW[ot][k] = *(const short8v*)&Wo[s * 16384 +
                             (ob + ot * 16 + l15) * 128 + k * 32 + kg * 8];
#pragma unroll
        for (int tt = 0; tt < 4; tt++) {
            short8v aX[4];
#pragma unroll
            for (int k = 0; k < 4; k++)
                aX[k] = *(short8v*)&xT[(tt * 16 + l15) * 136 + k * 32 + kg * 8];
            f32x4 h0 = {0.f, 0.f, 0.f, 0.f}, h1 = {0.f, 0.f, 0.f, 0.f};
#pragma unroll
            for (int k = 0; k < 4; k++) {
                h0 = __builtin_amdgcn_mfma_f32_16x16x32_bf16(aX[k], bW[0][k], h0, 0, 0, 0);
                h1 = __builtin_amdgcn_mfma_f32_16x16x32_bf16(aX[k], bW[1][k], h1, 0, 0, 0);
            }
#pragma unroll
            for (int rr = 0; rr < 4; rr++) {
                int tv = tt * 16 + kg * 4 + rr;
                if (tv < 50) {
                    int tl = tv >= 25 ? 1 : 0, u = tv - tl * 25;
                    int n0 = tl * 128 + ob + l15;
                    int n1 = n0 + 16;
                    Bt[n0 * 32 + (((u >> 3) ^ ((n0 >> 1) & 3)) << 3) + (u & 7)] = f2bf(h0[rr]);
                    Bt[n1 * 32 + (((u >> 3) ^ ((n1 >> 1) & 3)) << 3) + (u & 7)] = f2bf(h1[rr]);
                }
            }
        }
        __syncthreads();
        // s2-part: A = attS (M=v), B = Bt (N=n'), one K-frag per s
        short8v aA[2];
#pragma unroll
        for (int mt = 0; mt < 2; mt++)
            aA[mt] = *(const short8v*)(An + (mt * 16 + l15) * 96 + s * 32 + kg * 8);
#pragma unroll
        for (int jj = 0; jj < 4; jj++) {
            int nr = (jb + jj) * 16 + l15;
            short8v b = *(const short8v*)&Bt[nr * 32 + ((kg ^ ((nr >> 1) & 3)) << 3)];
#pragma unroll
            for (int mt = 0; mt < 2; mt++)
                accS[mt][jj] = __builtin_amdgcn_mfma_f32_16x16x32_bf16(aA[mt], b, accS[mt][jj], 0, 0, 0);
        }
        __syncthreads();
    }
    // y1 = lrelu(x + BN1(accS)) -> y1T[tv][o]
#pragma unroll
    for (int mt = 0; mt < 2; mt++)
#pragma unroll
        for (int jj = 0; jj < 4; jj++) {
            int nr = (jb + jj) * 16 + l15;
            int tl = nr >> 7, o = nr & 127;
            float sc = sc1[o], of = of1[o];
#pragma unroll
            for (int rr = 0; rr < 4; rr++) {
                int v = mt * 16 + kg * 4 + rr;
                if (v < 25) {
                    int tvl = tl * 25 + v;
                    float h = accS[mt][jj][rr] * sc + of + bf2f(xT[tvl * 136 + o]);
                    h = h > 0.f ? h : 0.1f * h;
                    y1T[tvl * 136 + o] = f2bf(h);
                }
            }
        }
    __syncthreads();
    // cbr-part: A = Wf (M=o'), B = y1T (N=tv)
    short8v aF[2][4];
#pragma unroll
    for (int mt = 0; mt < 2; mt++)
#pragma unroll
        for (int k = 0; k < 4; k++)
            aF[mt][k] = *(const short8v*)&Wf[(ob + mt * 16 + l15) * 128 + k * 32 + kg * 8];
    float* on = outp + (size_t)n * 204800;
#pragma unroll
    for (int nt = 0; nt < 4; nt++) {
        short8v bY[4];
#pragma unroll
        for (int k = 0; k < 4; k++)
            bY[k] = *(short8v*)&y1T[(nt * 16 + l15) * 136 + k * 32 + kg * 8];
        f32x4 c0 = {0.f, 0.f, 0.f, 0.f}, c1 = {0.f, 0.f, 0.f, 0.f};
#pragma unroll
        for (int k = 0; k < 4; k++) {
            c0 = __builtin_amdgcn_mfma_f32_16x16x32_bf16(aF[0][k], bY[k], c0, 0, 0, 0);
            c1 = __builtin_amdgcn_mfma_f32_16x16x32_bf16(aF[1][k], bY[k], c1, 0, 0, 0);
        }
        int tv = nt * 16 + l15;
        if (tv < 50) {
#pragma unroll
            for (int rr = 0; rr < 4; rr++) {
                {
                    int o = ob + kg * 4 + rr;
                    float h = c0[rr] * sc2[o] + of2[o] + bf2f(xT[tv * 136 + o]);
                    on[(size_t)o * 1600 + tvg0 + tv] = h > 0.f ? h : 0.1f * h;
                }
                {
                    int o = ob + 16 + kg * 4 + rr;
                    float h = c1[rr] * sc2[o] + of2[o] + bf2f(xT[tv * 136 + o]);
                    on[(size_t)o * 1600 + tvg0 + tv] = h > 0.f ? h : 0.1f * h;
                }
            }
        }
    }
}

// ------- t1 (MFMA, temporal): G[np][s][tv][128o] bf16 = sum_c Wbf[s][o][c] * src[c][tv] -------
__global__ __launch_bounds__(256) void t1_mfma(
    const float* __restrict__ src, const ushort* __restrict__ Wbf,
    ushort* __restrict__ G)
{
    __shared__ __align__(16) ushort xT[160 * 136];
    __shared__ __align__(16) ushort exch[2][16 * 136];
    const int np = blockIdx.y, tvb = blockIdx.x * 160;
    const float* sn = src + (size_t)np * 204800;
    for (int i = threadIdx.x; i < 2560; i += 256) {
        int tv4 = (i & 7) + (i >> 9) * 8;
        int cp  = (i >> 3) & 63;
        float4 a = *(const float4*)(sn + (2 * cp) * 1600 + tvb + tv4 * 4);
        float4 b = *(const float4*)(sn + (2 * cp + 1) * 1600 + tvb + tv4 * 4);
        float av[4] = { a.x, a.y, a.z, a.w };
        float bv[4] = { b.x, b.y, b.z, b.w };
#pragma unroll
        for (int e = 0; e < 4; e++) {
            uint p = (uint)f2bf(av[e]) | ((uint)f2bf(bv[e]) << 16);
            ((uint*)xT)[(tv4 * 4 + e) * 68 + cp] = p;
        }
    }
    __syncthreads();
    const int lane = threadIdx.x & 63, wave = threadIdx.x >> 6;
    const int l15 = lane & 15, kg = lane >> 4;
    const int o_base = wave * 32;
    int buf = 0;
    for (int s = 0; s < 3; s++) {
        short8v bfr[2][4];
#pragma unroll
        for (int nt = 0; nt < 2; nt++)
#pragma unroll
            for (int k = 0; k < 4; k++)
                bfr[nt][k] = *(const short8v*)&Wbf[s * 16384 +
                              (o_base + nt * 16 + l15) * 128 + k * 32 + kg * 8];
        ushort* Gs = G + (size_t)(np * 3 + s) * 64 * 3200;
        for (int mt = 0; mt < 10; mt++) {
            short8v af[4];
#pragma unroll
            for (int k = 0; k < 4; k++)
                af[k] = *(short8v*)&xT[(mt * 16 + l15) * 136 + k * 32 + kg * 8];
            f32x4 acc0 = {0.f, 0.f, 0.f, 0.f};
            f32x4 acc1 = {0.f, 0.f, 0.f, 0.f};
#pragma unroll
            for (int k = 0; k < 4; k++) {
                acc0 = __builtin_amdgcn_mfma_f32_16x16x32_bf16(af[k], bfr[0][k], acc0, 0, 0, 0);
                acc1 = __builtin_amdgcn_mfma_f32_16x16x32_bf16(af[k], bfr[1][k], acc1, 0, 0, 0);
            }
#pragma unroll
            for (int r = 0; r < 4; r++) {
                exch[buf][(kg * 4 + r) * 136 + o_base + l15]      = f2bf(acc0[r]);
                exch[buf][(kg * 4 + r) * 136 + o_base + 16 + l15] = f2bf(acc1[r]);
            }
            __syncthreads();
            for (int i = threadIdx.x; i < 1024; i += 256) {
                int rl = i >> 6, col = i & 63;
                ((uint*)(Gs + (size_t)(tvb + mt * 16 + rl) * 128))[col] =
                    ((const uint*)&exch[buf][rl * 136])[col];
            }
            buf ^= 1;
        }
    }
}

// ------- t2 (MFMA): pre[(q*25+v)][128o] = BN( sum_{st} attT_bf[q][st] * G[st][v][o] ) -------
__global__ __launch_bounds__(256) void t2_mfma(
    const ushort* __restrict__ G, const ushort* __restrict__ attT,
    const float* __restrict__ bnp, const float* __restrict__ bo,
    ushort* __restrict__ pre)
{
    __shared__ __align__(16) ushort Bt[128 * 256]; // [o][k swz], stride 256
    __shared__ float sc_l[128], of_l[128];
    const int v = blockIdx.x, np = blockIdx.y;
    if (threadIdx.x < 128) {
        int o = threadIdx.x;
        float sc = bnp[o] * rsqrtf(bnp[384 + o] + 1e-5f);
        sc_l[o] = sc;
        of_l[o] = (bo[o] - bnp[256 + o]) * sc + bnp[128 + o];
    }
    const int lane = threadIdx.x & 63, wave = threadIdx.x >> 6;
    const int l15 = lane & 15, kg = lane >> 4;
    const ushort* An = attT + (size_t)np * 12288;
    short8v a[4][6];
#pragma unroll
    for (int mt = 0; mt < 4; mt++)
#pragma unroll
        for (int ks = 0; ks < 6; ks++)
            a[mt][ks] = *(const short8v*)(An + (mt * 16 + l15) * 192 + ks * 32 + kg * 8);
    const ushort* Gq = G + (size_t)np * 192 * 3200 + v * 128;
    for (int i = threadIdx.x; i < 12288; i += 256) {
        int op = i & 63, st = i >> 6;
        uint w = *(const uint*)(Gq + st * 3200 + op * 2);
        int o0 = op * 2;
        int base = o0 * 256 + (((st >> 3) ^ ((o0 >> 1) & 7)) << 3) + (st & 7);
        Bt[base]       = (ushort)(w & 0xffffu);
        Bt[base + 256] = (ushort)(w >> 16);
    }
    __syncthreads();
    f32x4 acc[4][2];
#pragma unroll
    for (int mt = 0; mt < 4; mt++)
#pragma unroll
        for (int jj = 0; jj < 2; jj++) acc[mt][jj] = (f32x4){0.f, 0.f, 0.f, 0.f};
    const int jb = wave * 2;
#pragma unroll
    for (int ks = 0; ks < 6; ks++) {
        short8v b[2];
#pragma unroll
        for (int jj = 0; jj < 2; jj++) {
            int o = (jb + jj) * 16 + l15;
            b[jj] = *(const short8v*)&Bt[o * 256 + ((((ks * 4 + kg) ^ ((o >> 1) & 7))) << 3)];
        }
#pragma unroll
        for (int mt = 0; mt < 4; mt++)
#pragma unroll
            for (int jj = 0; jj < 2; jj++)
                acc[mt][jj] = __builtin_amdgcn_mfma_f32_16x16x32_bf16(a[mt][ks], b[jj], acc[mt][jj], 0, 0, 0);
    }
    ushort* pq = pre + (size_t)np * 204800;
#pragma unroll
    for (int mt = 0; mt < 4; mt++)
#pragma unroll
        for (int jj = 0; jj < 2; jj++) {
            int o = (jb + jj) * 16 + l15;
            float sc = sc_l[o], of = of_l[o];
#pragma unroll
            for (int rr = 0; rr < 4; rr++) {
                int q = mt * 16 + kg * 4 + rr;
                pq[(q * 25 + v) * 128 + o] = f2bf(acc[mt][jj][rr] * sc + of);
            }
        }
}

// ------- cbr (MFMA, temporal): out = lrelu(res + BN2(Wf @ lrelu(res + pre) + b)) -------
__global__ __launch_bounds__(256) void cbr_mfma(
    const ushort* __restrict__ pre, const float* res,
    const ushort* __restrict__ Wbf, const float* __restrict__ bias,
    const float* __restrict__ bnp, float* outp)
{
    __shared__ __align__(16) ushort xT[160 * 136];
    __shared__ float sc_l[128], of_l[128];
    const int np = blockIdx.y, tvb = blockIdx.x * 160;
    if (threadIdx.x < 128) {
        int o = threadIdx.x;
        float sc = bnp[o] * rsqrtf(bnp[384 + o] + 1e-5f);
        sc_l[o] = sc;
        of_l[o] = (bias[o] - bnp[256 + o]) * sc + bnp[128 + o];
    }
    const ushort* pp = pre + (size_t)np * 204800 + (size_t)tvb * 128;
    for (int i = threadIdx.x; i < 10240; i += 256) {
        int tl = i >> 6, cp = i & 63;
        ((uint*)xT)[tl * 68 + cp] = *(const uint*)(pp + tl * 128 + cp * 2);
    }
    __syncthreads();
    const float* rq = res + (size_t)np * 204800;
    for (int i = threadIdx.x; i < 5120; i += 256) {
        int tv = i % 160, cq = i / 160, c = cq * 4;
        uint2 w = *(uint2*)&xT[tv * 136 + c];
        float h0 = rq[(size_t)(c + 0) * 1600 + tvb + tv] + bf2f((ushort)(w.x & 0xffffu));
        float h1 = rq[(size_t)(c + 1) * 1600 + tvb + tv] + bf2f((ushort)(w.x >> 16));
        float h2 = rq[(size_t)(c + 2) * 1600 + tvb + tv] + bf2f((ushort)(w.y & 0xffffu));
        float h3 = rq[(size_t)(c + 3) * 1600 + tvb + tv] + bf2f((ushort)(w.y >> 16));
        h0 = h0 > 0.f ? h0 : 0.1f * h0;
        h1 = h1 > 0.f ? h1 : 0.1f * h1;
        h2 = h2 > 0.f ? h2 : 0.1f * h2;
        h3 = h3 > 0.f ? h3 : 0.1f * h3;
        w.x = (uint)f2bf(h0) | ((uint)f2bf(h1) << 16);
        w.y = (uint)f2bf(h2) | ((uint)f2bf(h3) << 16);
        *(uint2*)&xT[tv * 136 + c] = w;
    }
    __syncthreads();
    const int lane = threadIdx.x & 63, wave = threadIdx.x >> 6;
    const int l15 = lane & 15, kg = lane >> 4;
    const int ob = wave * 32;
    short8v af[2][4];
#pragma unroll
    for (int mt = 0; mt < 2; mt++)
#pragma unroll
        for (int k = 0; k < 4; k++)
            af[mt][k] = *(const short8v*)&Wbf[(ob + mt * 16 + l15) * 128 + k * 32 + kg * 8];
    for (int nt = 0; nt < 10; nt++) {
        short8v bfg[4];
#pragma unroll
        for (int k = 0; k < 4; k++)
            bfg[k] = *(short8v*)&xT[(nt * 16 + l15) * 136 + k * 32 + kg * 8];
        f32x4 acc0 = {0.f, 0.f, 0.f, 0.f};
        f32x4 acc1 = {0.f, 0.f, 0.f, 0.f};
#pragma unroll
        for (int k = 0; k < 4; k++) {
            acc0 = __builtin_amdgcn_mfma_f32_16x16x32_bf16(af[0][k], bfg[k], acc0, 0, 0, 0);
            acc1 = __builtin_amdgcn_mfma_f32_16x16x32_bf16(af[1][k], bfg[k], acc1, 0, 0, 0);
        }
        int tv = tvb + nt * 16 + l15;
#pragma unroll
        for (int rr = 0; rr < 4; rr++) {
            {
                int o = ob + kg * 4 + rr;
                size_t idx = (size_t)np * 204800 + (size_t)o * 1600 + tv;
                float h = acc0[rr] * sc_l[o] + of_l[o] + res[idx];
                outp[idx] = h > 0.f ? h : 0.1f * h;
            }
            {
                int o = ob + 16 + kg * 4 + rr;
                size_t idx = (size_t)np * 204800 + (size_t)o * 1600 + tv;
                float h = acc1[rr] * sc_l[o] + of_l[o] + res[idx];
                outp[idx] = h > 0.f ? h : 0.1f * h;
            }
        }
    }
}

extern "C" void kernel_launch(void* const* d_in, const int* in_sizes, int n_in,
                              void* d_out, int out_size, void* d_ws, size_t ws_size,
                              hipStream_t stream)
{
    (void)in_sizes; (void)n_in; (void)out_size; (void)ws_size;
    const float* x      = (const float*)d_in[0];
    const float* Wqk_s  = (const float*)d_in[1];
    const float* bqk_s  = (const float*)d_in[2];
    const float* alphas = (const float*)d_in[3];
    const float* att0s  = (const float*)d_in[4];
    const float* Wo_s   = (const float*)d_in[5];
    const float* bo_s   = (const float*)d_in[6];
    const float* bn_o_s = (const float*)d_in[7];
    const float* Wf_s   = (const float*)d_in[8];
    const float* bf_s   = (const float*)d_in[9];
    const float* bn_f_s = (const float*)d_in[10];
    const float* Wqk_t  = (const float*)d_in[11];
    const float* bqk_t  = (const float*)d_in[12];
    const float* alphat = (const float*)d_in[13];
    const float* att0t  = (const float*)d_in[14];
    const float* Wo_t   = (const float*)d_in[15];
    const float* bo_t   = (const float*)d_in[16];
    const float* bn_o_t = (const float*)d_in[17];
    const float* Wf_t   = (const float*)d_in[18];
    const float* bf_t   = (const float*)d_in[19];
    const float* bn_f_t = (const float*)d_in[20];

    float* out = (float*)d_out;
    const size_t CTV = 204800;
    ushort* qk      = (ushort*)d_ws;
    ushort* Gbuf    = (ushort*)d_ws;                       // temporal, overlays dead qk
    ushort* pre     = (ushort*)((char*)d_ws + 39321600);   // temporal
    ushort* attS_bf = (ushort*)((char*)d_ws + 78643200);
    ushort* attT_bf = (ushort*)((char*)d_ws + 79603200);
    ushort* W16     = (ushort*)((char*)d_ws + 85894656);
    const ushort* WoS_bf  = W16;
    const ushort* WfS_bf  = W16 + 49152;
    const ushort* WoT_bf  = W16 + 65536;
    const ushort* WfT_bf  = W16 + 114688;
    const ushort* WqkS_bf = W16 + 131072;
    const ushort* WqkT_bf = W16 + 155648;

    wt_prep<<<704, 256, 0, stream>>>(Wo_s, Wf_s, Wo_t, Wf_t, Wqk_s, Wqk_t, W16);

    dim3 gqk(10, 128), gatt(3, 128), gsf(32, 128), gt1(10, 32), gt2(25, 32), gcbr(10, 32);

    // ---- spatial (fully fused post-attention) ----
    qk_pe_mfma<<<gqk, 256, 0, stream>>>(x, WqkS_bf, bqk_s, qk, 0);
    att_s_mfma<<<gatt, 256, 0, stream>>>(qk, alphas, att0s, attS_bf);
    s_fused<<<gsf, 256, 0, stream>>>(x, WoS_bf, attS_bf, WfS_bf,
                                     bn_o_s, bo_s, bn_f_s, bf_s, out);

    // ---- temporal ----
    qk_pe_mfma<<<gqk, 256, 0, stream>>>(out, WqkT_bf, bqk_t, qk, 1);
    att_t_mfma<<<gatt, 256, 0, stream>>>(qk, alphat, att0t, attT_bf);
    for (int h = 0; h < 4; h++) {
        size_t n0 = (size_t)h * 32;
        t1_mfma<<<gt1, 256, 0, stream>>>(out + n0 * CTV, WoT_bf, Gbuf);
        t2_mfma<<<gt2, 256, 0, stream>>>(Gbuf, attT_bf + n0 * 12288, bn_o_t, bo_t, pre);
        cbr_mfma<<<gcbr, 256, 0, stream>>>(pre, out + n0 * CTV, WfT_bf, bf_t, bn_f_t,
                                           out + n0 * CTV);
    }
}

// Round 11
// 591.894 us; speedup vs baseline: 1.6560x; 1.2286x over previous
//
#include <hip/hip_runtime.h>
#include <math.h>

// Dims: N=128, C=128, T=64, V=25, S=3, R=32; TV=1600, CTV=204800.
// qk: [n][192r][1600tv] bf16. attS_bf: [n][32v][96k] (k=s*32+u). attT_bf: [n][64q][192k] (k=s*64+t).
// Spatial post-att: s_fused (t1+s2+cbr in LDS). Temporal: tt_fused (t1+t2 per (n,v), G in LDS) + cbr.
// pre: [n][1600tv][128o] bf16 at ws[0] (overlays dead qk).

typedef __attribute__((ext_vector_type(8))) short short8v;
typedef __attribute__((ext_vector_type(4))) float f32x4;

__device__ __forceinline__ ushort f2bf(float f) {
    uint b = __float_as_uint(f);
    uint r = b + 0x7fffu + ((b >> 16) & 1u);
    return (ushort)(r >> 16);
}
__device__ __forceinline__ float bf2f(ushort h) {
    return __uint_as_float(((uint)h) << 16);
}

// -------- weight prep (bf16 copies) --------
__global__ __launch_bounds__(256) void wt_prep(
    const float* __restrict__ Wo_s, const float* __restrict__ Wf_s,
    const float* __restrict__ Wo_t, const float* __restrict__ Wf_t,
    const float* __restrict__ Wqk_s, const float* __restrict__ Wqk_t,
    ushort* __restrict__ W16)
{
    int idx = blockIdx.x * 256 + threadIdx.x;
    if (idx >= 180224) return;
    float v;
    if (idx < 49152) {
        int s = idx / 16384, rem = idx % 16384, o = rem / 128, c = rem % 128;
        v = Wo_s[o * 384 + s * 128 + c];
    } else if (idx < 65536) {
        v = Wf_s[idx - 49152];
    } else if (idx < 114688) {
        int i = idx - 65536, s = i / 16384, rem = i % 16384, o = rem / 128, c = rem % 128;
        v = Wo_t[o * 384 + s * 128 + c];
    } else if (idx < 131072) {
        v = Wf_t[idx - 114688];
    } else if (idx < 155648) {
        v = Wqk_s[idx - 131072];
    } else {
        v = Wqk_t[idx - 155648];
    }
    W16[idx] = f2bf(v);
}

// -------- qk_pe (MFMA): qk[n][192r][1600tv] --------
__global__ __launch_bounds__(256) void qk_pe_mfma(
    const float* __restrict__ src, const ushort* __restrict__ Wbf,
    const float* __restrict__ bias, ushort* __restrict__ out, int pos_is_t)
{
    __shared__ __align__(16) ushort xT[160 * 136];
    __shared__ __align__(16) ushort exch[192 * 24];
    const int n = blockIdx.y, tvb = blockIdx.x * 160;
    const float* sn = src + (size_t)n * 204800;
    for (int i = threadIdx.x; i < 2560; i += 256) {
        int tv4 = (i & 7) + (i >> 9) * 8;   // 0..39
        int cp  = (i >> 3) & 63;            // c-pair 0..63
        float4 a = *(const float4*)(sn + (2 * cp) * 1600 + tvb + tv4 * 4);
        float4 b = *(const float4*)(sn + (2 * cp + 1) * 1600 + tvb + tv4 * 4);
        float dv = __expf(-0.14391156831212787f * (float)cp);
        float av[4] = { a.x, a.y, a.z, a.w };
        float bv[4] = { b.x, b.y, b.z, b.w };
#pragma unroll
        for (int e = 0; e < 4; e++) {
            int tv = tvb + tv4 * 4 + e;
            int tt = tv / 25;
            float pos = pos_is_t ? (float)tt : (float)(tv - tt * 25);
            float ang = pos * dv;
            uint p = (uint)f2bf(av[e] + __sinf(ang)) | ((uint)f2bf(bv[e] + __cosf(ang)) << 16);
            ((uint*)xT)[(tv4 * 4 + e) * 68 + cp] = p;
        }
    }
    __syncthreads();
    const int lane = threadIdx.x & 63, wave = threadIdx.x >> 6;
    const int l15 = lane & 15, kg = lane >> 4;
    const int rb = wave * 48;
    short8v wf[3][4];
#pragma unroll
    for (int nt = 0; nt < 3; nt++)
#pragma unroll
        for (int k = 0; k < 4; k++)
            wf[nt][k] = *(const short8v*)&Wbf[(rb + nt * 16 + l15) * 128 + k * 32 + kg * 8];
    float bsv[3];
#pragma unroll
    for (int nt = 0; nt < 3; nt++) bsv[nt] = bias[rb + nt * 16 + l15];
    ushort* on = out + (size_t)n * 307200;
    for (int mt = 0; mt < 10; mt++) {
        short8v af[4];
#pragma unroll
        for (int k = 0; k < 4; k++)
            af[k] = *(short8v*)&xT[(mt * 16 + l15) * 136 + k * 32 + kg * 8];
        f32x4 accs[3];
#pragma unroll
        for (int nt = 0; nt < 3; nt++) {
            f32x4 acc = {0.f, 0.f, 0.f, 0.f};
#pragma unroll
            for (int k = 0; k < 4; k++)
                acc = __builtin_amdgcn_mfma_f32_16x16x32_bf16(af[k], wf[nt][k], acc, 0, 0, 0);
            accs[nt] = acc;
        }
        __syncthreads();
#pragma unroll
        for (int nt = 0; nt < 3; nt++) {
            uint2 pk;
            pk.x = (uint)f2bf(accs[nt][0] + bsv[nt]) | ((uint)f2bf(accs[nt][1] + bsv[nt]) << 16);
            pk.y = (uint)f2bf(accs[nt][2] + bsv[nt]) | ((uint)f2bf(accs[nt][3] + bsv[nt]) << 16);
            *(uint2*)&exch[(rb + nt * 16 + l15) * 24 + kg * 4] = pk;
        }
        __syncthreads();
        for (int i = threadIdx.x; i < 384; i += 256) {
            int r = i >> 1, hh = i & 1;
            *(uint4*)(on + (size_t)r * 1600 + tvb + mt * 16 + hh * 8) =
                *(const uint4*)&exch[r * 24 + hh * 8];
        }
    }
}

// -------- att_s (MFMA) -> attS_bf[n][32v][96k] bf16, k=s*32+u, pads zeroed --------
__global__ __launch_bounds__(256) void att_s_mfma(
    const ushort* __restrict__ qk, const float* __restrict__ alphas,
    const float* __restrict__ att0, ushort* __restrict__ attS_bf)
{
    __shared__ __align__(16) ushort Qs[32 * 520];
    __shared__ __align__(16) ushort Ks[32 * 520];
    const int s = blockIdx.x, n = blockIdx.y;
    const ushort* qb = qk + (size_t)n * 307200 + (size_t)(s * 32) * 1600;
    const ushort* kb = qb + 96 * 1600;
    for (int i = threadIdx.x; i < 3072; i += 256) {
        int v = i / 96, k = i - v * 96;
        if (v >= 25 || (k & 31) >= 25) attS_bf[(size_t)n * 3072 + i] = 0;
    }
    const int lane = threadIdx.x & 63, wave = threadIdx.x >> 6;
    const int l15 = lane & 15, kg = lane >> 4;
    const int mt = wave >> 1, nt = wave & 1;
    f32x4 acc = {0.f, 0.f, 0.f, 0.f};
    for (int rc = 0; rc < 4; rc++) {
        __syncthreads();
        for (int i = threadIdx.x; i < 6400; i += 256) {
            int rl = i / 800, j = i - rl * 800;
            uint uq = *(const uint*)(qb + (rc * 8 + rl) * 1600 + j * 2);
            uint uk = *(const uint*)(kb + (rc * 8 + rl) * 1600 + j * 2);
            int tv = j * 2;
            int t0 = tv / 25, u0 = tv - t0 * 25;
            int t1 = (tv + 1) / 25, u1 = (tv + 1) - t1 * 25;
            Qs[u0 * 520 + rl * 64 + t0] = (ushort)(uq & 0xffffu);
            Qs[u1 * 520 + rl * 64 + t1] = (ushort)(uq >> 16);
            Ks[u0 * 520 + rl * 64 + t0] = (ushort)(uk & 0xffffu);
            Ks[u1 * 520 + rl * 64 + t1] = (ushort)(uk >> 16);
        }
        __syncthreads();
#pragma unroll
        for (int ks = 0; ks < 16; ks++) {
            short8v a = *(const short8v*)&Qs[(mt * 16 + l15) * 520 + ks * 32 + kg * 8];
            short8v b = *(const short8v*)&Ks[(nt * 16 + l15) * 520 + ks * 32 + kg * 8];
            acc = __builtin_amdgcn_mfma_f32_16x16x32_bf16(a, b, acc, 0, 0, 0);
        }
    }
    float alpha = alphas[s];
#pragma unroll
    for (int rr = 0; rr < 4; rr++) {
        int u = mt * 16 + kg * 4 + rr, v = nt * 16 + l15;
        if (u < 25 && v < 25)
            attS_bf[(size_t)n * 3072 + v * 96 + s * 32 + u] =
                f2bf(tanhf(acc[rr] * (1.0f / 2048.0f)) * alpha + att0[s * 625 + u * 25 + v]);
    }
}

// -------- att_t (MFMA) -> attT_bf[n][64q][192k] bf16, k=s*64+t --------
__global__ __launch_bounds__(256) void att_t_mfma(
    const ushort* __restrict__ qk, const float* __restrict__ alphat,
    const float* __restrict__ att0, ushort* __restrict__ attT_bf)
{
    __shared__ __align__(16) ushort Qt[8 * 64 * 40];
    __shared__ __align__(16) ushort Kt[8 * 64 * 40];
    const int s = blockIdx.x, n = blockIdx.y;
    const ushort* qb = qk + (size_t)n * 307200 + (size_t)(s * 32) * 1600;
    const ushort* kb = qb + 96 * 1600;
    for (int i = threadIdx.x; i < 10240; i += 256) {
        ((uint*)Qt)[i] = 0u;
        ((uint*)Kt)[i] = 0u;
    }
    const int lane = threadIdx.x & 63, wave = threadIdx.x >> 6;
    const int l15 = lane & 15, kg = lane >> 4;
    const int mt = wave;
    f32x4 acc[4];
#pragma unroll
    for (int i = 0; i < 4; i++) acc[i] = (f32x4){0.f, 0.f, 0.f, 0.f};
    for (int rc = 0; rc < 4; rc++) {
        __syncthreads();
        for (int i = threadIdx.x; i < 6400; i += 256) {
            int rl = i / 800, j = i - rl * 800;
            uint uq = *(const uint*)(qb + (rc * 8 + rl) * 1600 + j * 2);
            uint uk = *(const uint*)(kb + (rc * 8 + rl) * 1600 + j * 2);
            int tv = j * 2;
            int t0 = tv / 25, v0 = tv - t0 * 25;
            int t1 = (tv + 1) / 25, v1 = (tv + 1) - t1 * 25;
            Qt[(rl * 64 + t0) * 40 + v0] = (ushort)(uq & 0xffffu);
            Qt[(rl * 64 + t1) * 40 + v1] = (ushort)(uq >> 16);
            Kt[(rl * 64 + t0) * 40 + v0] = (ushort)(uk & 0xffffu);
            Kt[(rl * 64 + t1) * 40 + v1] = (ushort)(uk >> 16);
        }
        __syncthreads();
#pragma unroll
        for (int rl = 0; rl < 8; rl++) {
            short8v a = *(const short8v*)&Qt[(rl * 64 + mt * 16 + l15) * 40 + kg * 8];
#pragma unroll
            for (int nq = 0; nq < 4; nq++) {
                short8v b = *(const short8v*)&Kt[(rl * 64 + nq * 16 + l15) * 40 + kg * 8];
                acc[nq] = __builtin_amdgcn_mfma_f32_16x16x32_bf16(a, b, acc[nq], 0, 0, 0);
            }
        }
    }
    float alpha = alphat[s];
#pragma unroll
    for (int nq = 0; nq < 4; nq++) {
        int q = nq * 16 + l15;
        ushort w4[4];
#pragma unroll
        for (int rr = 0; rr < 4; rr++) {
            int t = mt * 16 + kg * 4 + rr;
            w4[rr] = f2bf(tanhf(acc[nq][rr] * (1.0f / 800.0f)) * alpha +
                          att0[s * 4096 + t * 64 + q]);
        }
        uint2 pk;
        pk.x = (uint)w4[0] | ((uint)w4[1] << 16);
        pk.y = (uint)w4[2] | ((uint)w4[3] << 16);
        *(uint2*)(attT_bf + (size_t)n * 12288 + q * 192 + s * 64 + mt * 16 + kg * 4) = pk;
    }
}

// ------- s_fused: whole spatial post-attention, one block per (n, 2t) -------
__global__ __launch_bounds__(256) void s_fused(
    const float* __restrict__ x, const ushort* __restrict__ Wo /*[3][128o][128c]*/,
    const ushort* __restrict__ attS /*[n][32v][96k]*/, const ushort* __restrict__ Wf,
    const float* __restrict__ bnO, const float* __restrict__ boO,
    const float* __restrict__ bnF, const float* __restrict__ bfF,
    float* __restrict__ outp)
{
    __shared__ __align__(16) ushort xT[64 * 136];   // [tv_local][c] (rows 50..63 unused)
    __shared__ __align__(16) ushort Bt[256 * 32];   // [n'=(tl,o)][k=u swz] per s
    __shared__ __align__(16) ushort y1T[64 * 136];
    __shared__ float sc1[128], of1[128], sc2[128], of2[128];
    const int n = blockIdx.y, tb = blockIdx.x;
    const int tvg0 = tb * 50;
    if (threadIdx.x < 128) {
        int o = threadIdx.x;
        float s1 = bnO[o] * rsqrtf(bnO[384 + o] + 1e-5f);
        sc1[o] = s1; of1[o] = (boO[o] - bnO[256 + o]) * s1 + bnO[128 + o];
    } else {
        int o = threadIdx.x - 128;
        float s2 = bnF[o] * rsqrtf(bnF[384 + o] + 1e-5f);
        sc2[o] = s2; of2[o] = (bfF[o] - bnF[256 + o]) * s2 + bnF[128 + o];
    }
    for (int i = threadIdx.x; i < 1792; i += 256) {
        int nr = i / 7, k = 25 + i % 7;
        Bt[nr * 32 + (((k >> 3) ^ ((nr >> 1) & 3)) << 3) + (k & 7)] = 0;
    }
    const float* xn = x + (size_t)n * 204800;
    for (int i = threadIdx.x; i < 3200; i += 256) {
        int c = i / 25, j2 = i - c * 25;
        float2 v2 = *(const float2*)(xn + c * 1600 + tvg0 + j2 * 2);
        xT[(j2 * 2) * 136 + c]     = f2bf(v2.x);
        xT[(j2 * 2 + 1) * 136 + c] = f2bf(v2.y);
    }
    __syncthreads();
    const int lane = threadIdx.x & 63, wave = threadIdx.x >> 6;
    const int l15 = lane & 15, kg = lane >> 4;
    const int ob = wave * 32, jb = wave * 4;
    f32x4 accS[2][4];
#pragma unroll
    for (int mt = 0; mt < 2; mt++)
#pragma unroll
        for (int jj = 0; jj < 4; jj++) accS[mt][jj] = (f32x4){0.f, 0.f, 0.f, 0.f};
    const ushort* An = attS + (size_t)n * 3072;
    for (int s = 0; s < 3; s++) {
        short8v bW[2][4];
#pragma unroll
        for (int ot = 0; ot < 2; ot++)
#pragma unroll
            for (int k = 0; k < 4; k++)
                bW[ot][k] = *(const short8v*)&Wo[s * 16384 +
                             (ob + ot * 16 + l15) * 128 + k * 32 + kg * 8];
#pragma unroll
        for (int tt = 0; tt < 4; tt++) {
            short8v aX[4];
#pragma unroll
            for (int k = 0; k < 4; k++)
                aX[k] = *(short8v*)&xT[(tt * 16 + l15) * 136 + k * 32 + kg * 8];
            f32x4 h0 = {0.f, 0.f, 0.f, 0.f}, h1 = {0.f, 0.f, 0.f, 0.f};
#pragma unroll
            for (int k = 0; k < 4; k++) {
                h0 = __builtin_amdgcn_mfma_f32_16x16x32_bf16(aX[k], bW[0][k], h0, 0, 0, 0);
                h1 = __builtin_amdgcn_mfma_f32_16x16x32_bf16(aX[k], bW[1][k], h1, 0, 0, 0);
            }
#pragma unroll
            for (int rr = 0; rr < 4; rr++) {
                int tv = tt * 16 + kg * 4 + rr;
                if (tv < 50) {
                    int tl = tv >= 25 ? 1 : 0, u = tv - tl * 25;
                    int n0 = tl * 128 + ob + l15;
                    int n1 = n0 + 16;
                    Bt[n0 * 32 + (((u >> 3) ^ ((n0 >> 1) & 3)) << 3) + (u & 7)] = f2bf(h0[rr]);
                    Bt[n1 * 32 + (((u >> 3) ^ ((n1 >> 1) & 3)) << 3) + (u & 7)] = f2bf(h1[rr]);
                }
            }
        }
        __syncthreads();
        short8v aA[2];
#pragma unroll
        for (int mt = 0; mt < 2; mt++)
            aA[mt] = *(const short8v*)(An + (mt * 16 + l15) * 96 + s * 32 + kg * 8);
#pragma unroll
        for (int jj = 0; jj < 4; jj++) {
            int nr = (jb + jj) * 16 + l15;
            short8v b = *(const short8v*)&Bt[nr * 32 + ((kg ^ ((nr >> 1) & 3)) << 3)];
#pragma unroll
            for (int mt = 0; mt < 2; mt++)
                accS[mt][jj] = __builtin_amdgcn_mfma_f32_16x16x32_bf16(aA[mt], b, accS[mt][jj], 0, 0, 0);
        }
        __syncthreads();
    }
#pragma unroll
    for (int mt = 0; mt < 2; mt++)
#pragma unroll
        for (int jj = 0; jj < 4; jj++) {
            int nr = (jb + jj) * 16 + l15;
            int tl = nr >> 7, o = nr & 127;
            float sc = sc1[o], of = of1[o];
#pragma unroll
            for (int rr = 0; rr < 4; rr++) {
                int v = mt * 16 + kg * 4 + rr;
                if (v < 25) {
                    int tvl = tl * 25 + v;
                    float h = accS[mt][jj][rr] * sc + of + bf2f(xT[tvl * 136 + o]);
                    h = h > 0.f ? h : 0.1f * h;
                    y1T[tvl * 136 + o] = f2bf(h);
                }
            }
        }
    __syncthreads();
    short8v aF[2][4];
#pragma unroll
    for (int mt = 0; mt < 2; mt++)
#pragma unroll
        for (int k = 0; k < 4; k++)
            aF[mt][k] = *(const short8v*)&Wf[(ob + mt * 16 + l15) * 128 + k * 32 + kg * 8];
    float* on = outp + (size_t)n * 204800;
#pragma unroll
    for (int nt = 0; nt < 4; nt++) {
        short8v bY[4];
#pragma unroll
        for (int k = 0; k < 4; k++)
            bY[k] = *(short8v*)&y1T[(nt * 16 + l15) * 136 + k * 32 + kg * 8];
        f32x4 c0 = {0.f, 0.f, 0.f, 0.f}, c1 = {0.f, 0.f, 0.f, 0.f};
#pragma unroll
        for (int k = 0; k < 4; k++) {
            c0 = __builtin_amdgcn_mfma_f32_16x16x32_bf16(aF[0][k], bY[k], c0, 0, 0, 0);
            c1 = __builtin_amdgcn_mfma_f32_16x16x32_bf16(aF[1][k], bY[k], c1, 0, 0, 0);
        }
        int tv = nt * 16 + l15;
        if (tv < 50) {
#pragma unroll
            for (int rr = 0; rr < 4; rr++) {
                {
                    int o = ob + kg * 4 + rr;
                    float h = c0[rr] * sc2[o] + of2[o] + bf2f(xT[tv * 136 + o]);
                    on[(size_t)o * 1600 + tvg0 + tv] = h > 0.f ? h : 0.1f * h;
                }
                {
                    int o = ob + 16 + kg * 4 + rr;
                    float h = c1[rr] * sc2[o] + of2[o] + bf2f(xT[tv * 136 + o]);
                    on[(size_t)o * 1600 + tvg0 + tv] = h > 0.f ? h : 0.1f * h;
                }
            }
        }
    }
}

// ------- tt_fused: temporal t1+t2 per (n, v). pre[(q*25+v)][o] = BN1(sum_{s,t} attT*G) -------
// G[s,t,o] = sum_c Wo_t[s,o,c] * y[c,t,v] computed in LDS per block; never hits HBM.
// Each wave owns 32 o-columns end-to-end (t1 writes them, t2 reads them).
__global__ __launch_bounds__(256) void tt_fused(
    const float* __restrict__ y, const ushort* __restrict__ Wo /*[3][128o][128c]*/,
    const ushort* __restrict__ attT /*[n][64q][192]*/,
    const float* __restrict__ bnp, const float* __restrict__ bo,
    ushort* __restrict__ pre)
{
    __shared__ __align__(16) ushort yS[64 * 136];   // [t][c]
    __shared__ __align__(16) ushort Gl[128 * 72];   // [o][64 t + 8 pad]
    __shared__ float sc_l[128], of_l[128];
    const int v = blockIdx.x, np = blockIdx.y;
    if (threadIdx.x < 128) {
        int o = threadIdx.x;
        float sc = bnp[o] * rsqrtf(bnp[384 + o] + 1e-5f);
        sc_l[o] = sc;
        of_l[o] = (bo[o] - bnp[256 + o]) * sc + bnp[128 + o];
    }
    const float* yq = y + (size_t)np * 204800;
    // stage y slice: yS[t][c] = y[c][t*25+v]  (strided reads; L2/L3 shared across v-blocks)
    for (int it = 0; it < 32; it++) {
        int idx = it * 256 + threadIdx.x;
        int c = idx >> 6, t = idx & 63;
        yS[t * 136 + c] = f2bf(yq[c * 1600 + t * 25 + v]);
    }
    __syncthreads();
    const int lane = threadIdx.x & 63, wave = threadIdx.x >> 6;
    const int l15 = lane & 15, kg = lane >> 4;
    const int ob = wave * 32;
    const ushort* An = attT + (size_t)np * 12288;
    f32x4 acc[4][2];
#pragma unroll
    for (int mt = 0; mt < 4; mt++)
#pragma unroll
        for (int jj = 0; jj < 2; jj++) acc[mt][jj] = (f32x4){0.f, 0.f, 0.f, 0.f};
    for (int s = 0; s < 3; s++) {
        // t1-part: G[t][o] for this wave's 32 o
        short8v bW[2][4];
#pragma unroll
        for (int nt = 0; nt < 2; nt++)
#pragma unroll
            for (int k = 0; k < 4; k++)
                bW[nt][k] = *(const short8v*)&Wo[s * 16384 +
                             (ob + nt * 16 + l15) * 128 + k * 32 + kg * 8];
#pragma unroll
        for (int mt = 0; mt < 4; mt++) {
            short8v aX[4];
#pragma unroll
            for (int k = 0; k < 4; k++)
                aX[k] = *(short8v*)&yS[(mt * 16 + l15) * 136 + k * 32 + kg * 8];
            f32x4 g0 = {0.f, 0.f, 0.f, 0.f}, g1 = {0.f, 0.f, 0.f, 0.f};
#pragma unroll
            for (int k = 0; k < 4; k++) {
                g0 = __builtin_amdgcn_mfma_f32_16x16x32_bf16(aX[k], bW[0][k], g0, 0, 0, 0);
                g1 = __builtin_amdgcn_mfma_f32_16x16x32_bf16(aX[k], bW[1][k], g1, 0, 0, 0);
            }
#pragma unroll
            for (int rr = 0; rr < 4; rr++) {
                int t = mt * 16 + kg * 4 + rr;
                Gl[(ob + l15) * 72 + t]      = f2bf(g0[rr]);
                Gl[(ob + 16 + l15) * 72 + t] = f2bf(g1[rr]);
            }
        }
        __syncthreads();   // (conservative: wave-private region, but cheap and safe)
        // t2-part: acc[q][o] += attT[q][s*64+t] * Gl[o][t]
#pragma unroll
        for (int ks = 0; ks < 2; ks++) {
            short8v b2[2];
#pragma unroll
            for (int jj = 0; jj < 2; jj++)
                b2[jj] = *(short8v*)&Gl[(ob + jj * 16 + l15) * 72 + ks * 32 + kg * 8];
#pragma unroll
            for (int mt = 0; mt < 4; mt++) {
                short8v a2 = *(const short8v*)(An + (mt * 16 + l15) * 192 + s * 64 + ks * 32 + kg * 8);
#pragma unroll
                for (int jj = 0; jj < 2; jj++)
                    acc[mt][jj] = __builtin_amdgcn_mfma_f32_16x16x32_bf16(a2, b2[jj], acc[mt][jj], 0, 0, 0);
            }
        }
        __syncthreads();
    }
    ushort* pq = pre + (size_t)np * 204800;
#pragma unroll
    for (int mt = 0; mt < 4; mt++)
#pragma unroll
        for (int jj = 0; jj < 2; jj++) {
            int o = ob + jj * 16 + l15;
            float sc = sc_l[o], of = of_l[o];
#pragma unroll
            for (int rr = 0; rr < 4; rr++) {
                int q = mt * 16 + kg * 4 + rr;
                pq[(q * 25 + v) * 128 + o] = f2bf(acc[mt][jj][rr] * sc + of);
            }
        }
}

// ------- cbr (MFMA, temporal): out = lrelu(res + BN2(Wf @ lrelu(res + pre) + b)) -------
__global__ __launch_bounds__(256) void cbr_mfma(
    const ushort* __restrict__ pre, const float* res,
    const ushort* __restrict__ Wbf, const float* __restrict__ bias,
    const float* __restrict__ bnp, float* outp)
{
    __shared__ __align__(16) ushort xT[160 * 136];
    __shared__ float sc_l[128], of_l[128];
    const int np = blockIdx.y, tvb = blockIdx.x * 160;
    if (threadIdx.x < 128) {
        int o = threadIdx.x;
        float sc = bnp[o] * rsqrtf(bnp[384 + o] + 1e-5f);
        sc_l[o] = sc;
        of_l[o] = (bias[o] - bnp[256 + o]) * sc + bnp[128 + o];
    }
    const ushort* pp = pre + (size_t)np * 204800 + (size_t)tvb * 128;
    for (int i = threadIdx.x; i < 10240; i += 256) {
        int tl = i >> 6, cp = i & 63;
        ((uint*)xT)[tl * 68 + cp] = *(const uint*)(pp + tl * 128 + cp * 2);
    }
    __syncthreads();
    const float* rq = res + (size_t)np * 204800;
    for (int i = threadIdx.x; i < 5120; i += 256) {
        int tv = i % 160, cq = i / 160, c = cq * 4;
        uint2 w = *(uint2*)&xT[tv * 136 + c];
        float h0 = rq[(size_t)(c + 0) * 1600 + tvb + tv] + bf2f((ushort)(w.x & 0xffffu));
        float h1 = rq[(size_t)(c + 1) * 1600 + tvb + tv] + bf2f((ushort)(w.x >> 16));
        float h2 = rq[(size_t)(c + 2) * 1600 + tvb + tv] + bf2f((ushort)(w.y & 0xffffu));
        float h3 = rq[(size_t)(c + 3) * 1600 + tvb + tv] + bf2f((ushort)(w.y >> 16));
        h0 = h0 > 0.f ? h0 : 0.1f * h0;
        h1 = h1 > 0.f ? h1 : 0.1f * h1;
        h2 = h2 > 0.f ? h2 : 0.1f * h2;
        h3 = h3 > 0.f ? h3 : 0.1f * h3;
        w.x = (uint)f2bf(h0) | ((uint)f2bf(h1) << 16);
        w.y = (uint)f2bf(h2) | ((uint)f2bf(h3) << 16);
        *(uint2*)&xT[tv * 136 + c] = w;
    }
    __syncthreads();
    const int lane = threadIdx.x & 63, wave = threadIdx.x >> 6;
    const int l15 = lane & 15, kg = lane >> 4;
    const int ob = wave * 32;
    short8v af[2][4];
#pragma unroll
    for (int mt = 0; mt < 2; mt++)
#pragma unroll
        for (int k = 0; k < 4; k++)
            af[mt][k] = *(const short8v*)&Wbf[(ob + mt * 16 + l15) * 128 + k * 32 + kg * 8];
    for (int nt = 0; nt < 10; nt++) {
        short8v bfg[4];
#pragma unroll
        for (int k = 0; k < 4; k++)
            bfg[k] = *(short8v*)&xT[(nt * 16 + l15) * 136 + k * 32 + kg * 8];
        f32x4 acc0 = {0.f, 0.f, 0.f, 0.f};
        f32x4 acc1 = {0.f, 0.f, 0.f, 0.f};
#pragma unroll
        for (int k = 0; k < 4; k++) {
            acc0 = __builtin_amdgcn_mfma_f32_16x16x32_bf16(af[0][k], bfg[k], acc0, 0, 0, 0);
            acc1 = __builtin_amdgcn_mfma_f32_16x16x32_bf16(af[1][k], bfg[k], acc1, 0, 0, 0);
        }
        int tv = tvb + nt * 16 + l15;
#pragma unroll
        for (int rr = 0; rr < 4; rr++) {
            {
                int o = ob + kg * 4 + rr;
                size_t idx = (size_t)np * 204800 + (size_t)o * 1600 + tv;
                float h = acc0[rr] * sc_l[o] + of_l[o] + res[idx];
                outp[idx] = h > 0.f ? h : 0.1f * h;
            }
            {
                int o = ob + 16 + kg * 4 + rr;
                size_t idx = (size_t)np * 204800 + (size_t)o * 1600 + tv;
                float h = acc1[rr] * sc_l[o] + of_l[o] + res[idx];
                outp[idx] = h > 0.f ? h : 0.1f * h;
            }
        }
    }
}

extern "C" void kernel_launch(void* const* d_in, const int* in_sizes, int n_in,
                              void* d_out, int out_size, void* d_ws, size_t ws_size,
                              hipStream_t stream)
{
    (void)in_sizes; (void)n_in; (void)out_size; (void)ws_size;
    const float* x      = (const float*)d_in[0];
    const float* Wqk_s  = (const float*)d_in[1];
    const float* bqk_s  = (const float*)d_in[2];
    const float* alphas = (const float*)d_in[3];
    const float* att0s  = (const float*)d_in[4];
    const float* Wo_s   = (const float*)d_in[5];
    const float* bo_s   = (const float*)d_in[6];
    const float* bn_o_s = (const float*)d_in[7];
    const float* Wf_s   = (const float*)d_in[8];
    const float* bf_s   = (const float*)d_in[9];
    const float* bn_f_s = (const float*)d_in[10];
    const float* Wqk_t  = (const float*)d_in[11];
    const float* bqk_t  = (const float*)d_in[12];
    const float* alphat = (const float*)d_in[13];
    const float* att0t  = (const float*)d_in[14];
    const float* Wo_t   = (const float*)d_in[15];
    const float* bo_t   = (const float*)d_in[16];
    const float* bn_o_t = (const float*)d_in[17];
    const float* Wf_t   = (const float*)d_in[18];
    const float* bf_t   = (const float*)d_in[19];
    const float* bn_f_t = (const float*)d_in[20];

    float* out = (float*)d_out;
    // ws layout (bytes):
    //  [0, 78,643,200)   qk bf16 [n][192][1600]; pre [n][1600][128] bf16 (52.4 MB)
    //                    overlays this region AFTER att_t consumed qk.
    //  [78,643,200, 79,429,632)  attS_bf
    //  [79,603,200, 82,748,928)  attT_bf
    //  [85,894,656, +360,448)    W16 bf16 weights
    ushort* qk      = (ushort*)d_ws;
    ushort* pre     = (ushort*)d_ws;
    ushort* attS_bf = (ushort*)((char*)d_ws + 78643200);
    ushort* attT_bf = (ushort*)((char*)d_ws + 79603200);
    ushort* W16     = (ushort*)((char*)d_ws + 85894656);
    const ushort* WoS_bf  = W16;
    const ushort* WfS_bf  = W16 + 49152;
    const ushort* WoT_bf  = W16 + 65536;
    const ushort* WfT_bf  = W16 + 114688;
    const ushort* WqkS_bf = W16 + 131072;
    const ushort* WqkT_bf = W16 + 155648;

    wt_prep<<<704, 256, 0, stream>>>(Wo_s, Wf_s, Wo_t, Wf_t, Wqk_s, Wqk_t, W16);

    dim3 gqk(10, 128), gatt(3, 128), gsf(32, 128), gtt(25, 128), gcbr(10, 128);

    // ---- spatial ----
    qk_pe_mfma<<<gqk, 256, 0, stream>>>(x, WqkS_bf, bqk_s, qk, 0);
    att_s_mfma<<<gatt, 256, 0, stream>>>(qk, alphas, att0s, attS_bf);
    s_fused<<<gsf, 256, 0, stream>>>(x, WoS_bf, attS_bf, WfS_bf,
                                     bn_o_s, bo_s, bn_f_s, bf_s, out);

    // ---- temporal ----
    qk_pe_mfma<<<gqk, 256, 0, stream>>>(out, WqkT_bf, bqk_t, qk, 1);
    att_t_mfma<<<gatt, 256, 0, stream>>>(qk, alphat, att0t, attT_bf);
    tt_fused<<<gtt, 256, 0, stream>>>(out, WoT_bf, attT_bf, bn_o_t, bo_t, pre);
    cbr_mfma<<<gcbr, 256, 0, stream>>>(pre, out, WfT_bf, bf_t, bn_f_t, out);
}

// Round 12
// 506.327 us; speedup vs baseline: 1.9358x; 1.1690x over previous
//
#include <hip/hip_runtime.h>
#include <math.h>

// Dims: N=128, C=128, T=64, V=25, S=3, R=32; TV=1600, CTV=204800.
// qk: [n][192r][1600tv] bf16. attS_bf: [n][32v][96k] (k=s*32+u). attT_bf: [n][64q][192k] (k=s*64+t).
// Spatial post-att: s_fused. Temporal: y_cvt -> tt_fused (t1+t2+res in LDS, y_bf->y1 in place) -> cbr.
// y_bf/y1: [n][1600tv][128c] bf16 at ws[0] (overlays dead qk after att_t).

typedef __attribute__((ext_vector_type(8))) short short8v;
typedef __attribute__((ext_vector_type(4))) float f32x4;

__device__ __forceinline__ ushort f2bf(float f) {
    uint b = __float_as_uint(f);
    uint r = b + 0x7fffu + ((b >> 16) & 1u);
    return (ushort)(r >> 16);
}
__device__ __forceinline__ float bf2f(ushort h) {
    return __uint_as_float(((uint)h) << 16);
}

// -------- weight prep (bf16 copies) --------
__global__ __launch_bounds__(256) void wt_prep(
    const float* __restrict__ Wo_s, const float* __restrict__ Wf_s,
    const float* __restrict__ Wo_t, const float* __restrict__ Wf_t,
    const float* __restrict__ Wqk_s, const float* __restrict__ Wqk_t,
    ushort* __restrict__ W16)
{
    int idx = blockIdx.x * 256 + threadIdx.x;
    if (idx >= 180224) return;
    float v;
    if (idx < 49152) {
        int s = idx / 16384, rem = idx % 16384, o = rem / 128, c = rem % 128;
        v = Wo_s[o * 384 + s * 128 + c];
    } else if (idx < 65536) {
        v = Wf_s[idx - 49152];
    } else if (idx < 114688) {
        int i = idx - 65536, s = i / 16384, rem = i % 16384, o = rem / 128, c = rem % 128;
        v = Wo_t[o * 384 + s * 128 + c];
    } else if (idx < 131072) {
        v = Wf_t[idx - 114688];
    } else if (idx < 155648) {
        v = Wqk_s[idx - 131072];
    } else {
        v = Wqk_t[idx - 155648];
    }
    W16[idx] = f2bf(v);
}

// -------- qk_pe (MFMA): qk[n][192r][1600tv] --------
__global__ __launch_bounds__(256) void qk_pe_mfma(
    const float* __restrict__ src, const ushort* __restrict__ Wbf,
    const float* __restrict__ bias, ushort* __restrict__ out, int pos_is_t)
{
    __shared__ __align__(16) ushort xT[160 * 136];
    __shared__ __align__(16) ushort exch[192 * 24];
    const int n = blockIdx.y, tvb = blockIdx.x * 160;
    const float* sn = src + (size_t)n * 204800;
    for (int i = threadIdx.x; i < 2560; i += 256) {
        int tv4 = (i & 7) + (i >> 9) * 8;   // 0..39
        int cp  = (i >> 3) & 63;            // c-pair 0..63
        float4 a = *(const float4*)(sn + (2 * cp) * 1600 + tvb + tv4 * 4);
        float4 b = *(const float4*)(sn + (2 * cp + 1) * 1600 + tvb + tv4 * 4);
        float dv = __expf(-0.14391156831212787f * (float)cp);
        float av[4] = { a.x, a.y, a.z, a.w };
        float bv[4] = { b.x, b.y, b.z, b.w };
#pragma unroll
        for (int e = 0; e < 4; e++) {
            int tv = tvb + tv4 * 4 + e;
            int tt = tv / 25;
            float pos = pos_is_t ? (float)tt : (float)(tv - tt * 25);
            float ang = pos * dv;
            uint p = (uint)f2bf(av[e] + __sinf(ang)) | ((uint)f2bf(bv[e] + __cosf(ang)) << 16);
            ((uint*)xT)[(tv4 * 4 + e) * 68 + cp] = p;
        }
    }
    __syncthreads();
    const int lane = threadIdx.x & 63, wave = threadIdx.x >> 6;
    const int l15 = lane & 15, kg = lane >> 4;
    const int rb = wave * 48;
    short8v wf[3][4];
#pragma unroll
    for (int nt = 0; nt < 3; nt++)
#pragma unroll
        for (int k = 0; k < 4; k++)
            wf[nt][k] = *(const short8v*)&Wbf[(rb + nt * 16 + l15) * 128 + k * 32 + kg * 8];
    float bsv[3];
#pragma unroll
    for (int nt = 0; nt < 3; nt++) bsv[nt] = bias[rb + nt * 16 + l15];
    ushort* on = out + (size_t)n * 307200;
    for (int mt = 0; mt < 10; mt++) {
        short8v af[4];
#pragma unroll
        for (int k = 0; k < 4; k++)
            af[k] = *(short8v*)&xT[(mt * 16 + l15) * 136 + k * 32 + kg * 8];
        f32x4 accs[3];
#pragma unroll
        for (int nt = 0; nt < 3; nt++) {
            f32x4 acc = {0.f, 0.f, 0.f, 0.f};
#pragma unroll
            for (int k = 0; k < 4; k++)
                acc = __builtin_amdgcn_mfma_f32_16x16x32_bf16(af[k], wf[nt][k], acc, 0, 0, 0);
            accs[nt] = acc;
        }
        __syncthreads();
#pragma unroll
        for (int nt = 0; nt < 3; nt++) {
            uint2 pk;
            pk.x = (uint)f2bf(accs[nt][0] + bsv[nt]) | ((uint)f2bf(accs[nt][1] + bsv[nt]) << 16);
            pk.y = (uint)f2bf(accs[nt][2] + bsv[nt]) | ((uint)f2bf(accs[nt][3] + bsv[nt]) << 16);
            *(uint2*)&exch[(rb + nt * 16 + l15) * 24 + kg * 4] = pk;
        }
        __syncthreads();
        for (int i = threadIdx.x; i < 384; i += 256) {
            int r = i >> 1, hh = i & 1;
            *(uint4*)(on + (size_t)r * 1600 + tvb + mt * 16 + hh * 8) =
                *(const uint4*)&exch[r * 24 + hh * 8];
        }
    }
}

// -------- att_s (MFMA) -> attS_bf[n][32v][96k] bf16, k=s*32+u, pads zeroed --------
__global__ __launch_bounds__(256) void att_s_mfma(
    const ushort* __restrict__ qk, const float* __restrict__ alphas,
    const float* __restrict__ att0, ushort* __restrict__ attS_bf)
{
    __shared__ __align__(16) ushort Qs[32 * 520];
    __shared__ __align__(16) ushort Ks[32 * 520];
    const int s = blockIdx.x, n = blockIdx.y;
    const ushort* qb = qk + (size_t)n * 307200 + (size_t)(s * 32) * 1600;
    const ushort* kb = qb + 96 * 1600;
    for (int i = threadIdx.x; i < 3072; i += 256) {
        int v = i / 96, k = i - v * 96;
        if (v >= 25 || (k & 31) >= 25) attS_bf[(size_t)n * 3072 + i] = 0;
    }
    const int lane = threadIdx.x & 63, wave = threadIdx.x >> 6;
    const int l15 = lane & 15, kg = lane >> 4;
    const int mt = wave >> 1, nt = wave & 1;
    f32x4 acc = {0.f, 0.f, 0.f, 0.f};
    for (int rc = 0; rc < 4; rc++) {
        __syncthreads();
        for (int i = threadIdx.x; i < 6400; i += 256) {
            int rl = i / 800, j = i - rl * 800;
            uint uq = *(const uint*)(qb + (rc * 8 + rl) * 1600 + j * 2);
            uint uk = *(const uint*)(kb + (rc * 8 + rl) * 1600 + j * 2);
            int tv = j * 2;
            int t0 = tv / 25, u0 = tv - t0 * 25;
            int t1 = (tv + 1) / 25, u1 = (tv + 1) - t1 * 25;
            Qs[u0 * 520 + rl * 64 + t0] = (ushort)(uq & 0xffffu);
            Qs[u1 * 520 + rl * 64 + t1] = (ushort)(uq >> 16);
            Ks[u0 * 520 + rl * 64 + t0] = (ushort)(uk & 0xffffu);
            Ks[u1 * 520 + rl * 64 + t1] = (ushort)(uk >> 16);
        }
        __syncthreads();
#pragma unroll
        for (int ks = 0; ks < 16; ks++) {
            short8v a = *(const short8v*)&Qs[(mt * 16 + l15) * 520 + ks * 32 + kg * 8];
            short8v b = *(const short8v*)&Ks[(nt * 16 + l15) * 520 + ks * 32 + kg * 8];
            acc = __builtin_amdgcn_mfma_f32_16x16x32_bf16(a, b, acc, 0, 0, 0);
        }
    }
    float alpha = alphas[s];
#pragma unroll
    for (int rr = 0; rr < 4; rr++) {
        int u = mt * 16 + kg * 4 + rr, v = nt * 16 + l15;
        if (u < 25 && v < 25)
            attS_bf[(size_t)n * 3072 + v * 96 + s * 32 + u] =
                f2bf(tanhf(acc[rr] * (1.0f / 2048.0f)) * alpha + att0[s * 625 + u * 25 + v]);
    }
}

// -------- att_t (MFMA) -> attT_bf[n][64q][192k] bf16, k=s*64+t --------
__global__ __launch_bounds__(256) void att_t_mfma(
    const ushort* __restrict__ qk, const float* __restrict__ alphat,
    const float* __restrict__ att0, ushort* __restrict__ attT_bf)
{
    __shared__ __align__(16) ushort Qt[8 * 64 * 40];
    __shared__ __align__(16) ushort Kt[8 * 64 * 40];
    const int s = blockIdx.x, n = blockIdx.y;
    const ushort* qb = qk + (size_t)n * 307200 + (size_t)(s * 32) * 1600;
    const ushort* kb = qb + 96 * 1600;
    for (int i = threadIdx.x; i < 10240; i += 256) {
        ((uint*)Qt)[i] = 0u;
        ((uint*)Kt)[i] = 0u;
    }
    const int lane = threadIdx.x & 63, wave = threadIdx.x >> 6;
    const int l15 = lane & 15, kg = lane >> 4;
    const int mt = wave;
    f32x4 acc[4];
#pragma unroll
    for (int i = 0; i < 4; i++) acc[i] = (f32x4){0.f, 0.f, 0.f, 0.f};
    for (int rc = 0; rc < 4; rc++) {
        __syncthreads();
        for (int i = threadIdx.x; i < 6400; i += 256) {
            int rl = i / 800, j = i - rl * 800;
            uint uq = *(const uint*)(qb + (rc * 8 + rl) * 1600 + j * 2);
            uint uk = *(const uint*)(kb + (rc * 8 + rl) * 1600 + j * 2);
            int tv = j * 2;
            int t0 = tv / 25, v0 = tv - t0 * 25;
            int t1 = (tv + 1) / 25, v1 = (tv + 1) - t1 * 25;
            Qt[(rl * 64 + t0) * 40 + v0] = (ushort)(uq & 0xffffu);
            Qt[(rl * 64 + t1) * 40 + v1] = (ushort)(uq >> 16);
            Kt[(rl * 64 + t0) * 40 + v0] = (ushort)(uk & 0xffffu);
            Kt[(rl * 64 + t1) * 40 + v1] = (ushort)(uk >> 16);
        }
        __syncthreads();
#pragma unroll
        for (int rl = 0; rl < 8; rl++) {
            short8v a = *(const short8v*)&Qt[(rl * 64 + mt * 16 + l15) * 40 + kg * 8];
#pragma unroll
            for (int nq = 0; nq < 4; nq++) {
                short8v b = *(const short8v*)&Kt[(rl * 64 + nq * 16 + l15) * 40 + kg * 8];
                acc[nq] = __builtin_amdgcn_mfma_f32_16x16x32_bf16(a, b, acc[nq], 0, 0, 0);
            }
        }
    }
    float alpha = alphat[s];
#pragma unroll
    for (int nq = 0; nq < 4; nq++) {
        int q = nq * 16 + l15;
        ushort w4[4];
#pragma unroll
        for (int rr = 0; rr < 4; rr++) {
            int t = mt * 16 + kg * 4 + rr;
            w4[rr] = f2bf(tanhf(acc[nq][rr] * (1.0f / 800.0f)) * alpha +
                          att0[s * 4096 + t * 64 + q]);
        }
        uint2 pk;
        pk.x = (uint)w4[0] | ((uint)w4[1] << 16);
        pk.y = (uint)w4[2] | ((uint)w4[3] << 16);
        *(uint2*)(attT_bf + (size_t)n * 12288 + q * 192 + s * 64 + mt * 16 + kg * 4) = pk;
    }
}

// ------- s_fused: whole spatial post-attention, one block per (n, 2t) -------
__global__ __launch_bounds__(256) void s_fused(
    const float* __restrict__ x, const ushort* __restrict__ Wo /*[3][128o][128c]*/,
    const ushort* __restrict__ attS /*[n][32v][96k]*/, const ushort* __restrict__ Wf,
    const float* __restrict__ bnO, const float* __restrict__ boO,
    const float* __restrict__ bnF, const float* __restrict__ bfF,
    float* __restrict__ outp)
{
    __shared__ __align__(16) ushort xT[64 * 136];   // [tv_local][c] (rows 50..63 unused)
    __shared__ __align__(16) ushort Bt[256 * 32];   // [n'=(tl,o)][k=u swz] per s
    __shared__ __align__(16) ushort y1T[64 * 136];
    __shared__ float sc1[128], of1[128], sc2[128], of2[128];
    const int n = blockIdx.y, tb = blockIdx.x;
    const int tvg0 = tb * 50;
    if (threadIdx.x < 128) {
        int o = threadIdx.x;
        float s1 = bnO[o] * rsqrtf(bnO[384 + o] + 1e-5f);
        sc1[o] = s1; of1[o] = (boO[o] - bnO[256 + o]) * s1 + bnO[128 + o];
    } else {
        int o = threadIdx.x - 128;
        float s2 = bnF[o] * rsqrtf(bnF[384 + o] + 1e-5f);
        sc2[o] = s2; of2[o] = (bfF[o] - bnF[256 + o]) * s2 + bnF[128 + o];
    }
    for (int i = threadIdx.x; i < 1792; i += 256) {
        int nr = i / 7, k = 25 + i % 7;
        Bt[nr * 32 + (((k >> 3) ^ ((nr >> 1) & 3)) << 3) + (k & 7)] = 0;
    }
    const float* xn = x + (size_t)n * 204800;
    for (int i = threadIdx.x; i < 3200; i += 256) {
        int c = i / 25, j2 = i - c * 25;
        float2 v2 = *(const float2*)(xn + c * 1600 + tvg0 + j2 * 2);
        xT[(j2 * 2) * 136 + c]     = f2bf(v2.x);
        xT[(j2 * 2 + 1) * 136 + c] = f2bf(v2.y);
    }
    __syncthreads();
    const int lane = threadIdx.x & 63, wave = threadIdx.x >> 6;
    const int l15 = lane & 15, kg = lane >> 4;
    const int ob = wave * 32, jb = wave * 4;
    f32x4 accS[2][4];
#pragma unroll
    for (int mt = 0; mt < 2; mt++)
#pragma unroll
        for (int jj = 0; jj < 4; jj++) accS[mt][jj] = (f32x4){0.f, 0.f, 0.f, 0.f};
    const ushort* An = attS + (size_t)n * 3072;
    for (int s = 0; s < 3; s++) {
        short8v bW[2][4];
#pragma unroll
        for (int ot = 0; ot < 2; ot++)
#pragma unroll
            for (int k = 0; k < 4; k++)
                bW[ot][k] = *(const short8v*)&Wo[s * 16384 +
                             (ob + ot * 16 + l15) * 128 + k * 32 + kg * 8];
#pragma unroll
        for (int tt = 0; tt < 4; tt++) {
            short8v aX[4];
#pragma unroll
            for (int k = 0; k < 4; k++)
                aX[k] = *(short8v*)&xT[(tt * 16 + l15) * 136 + k * 32 + kg * 8];
            f32x4 h0 = {0.f, 0.f, 0.f, 0.f}, h1 = {0.f, 0.f, 0.f, 0.f};
#pragma unroll
            for (int k = 0; k < 4; k++) {
                h0 = __builtin_amdgcn_mfma_f32_16x16x32_bf16(aX[k], bW[0][k], h0, 0, 0, 0);
                h1 = __builtin_amdgcn_mfma_f32_16x16x32_bf16(aX[k], bW[1][k], h1, 0, 0, 0);
            }
#pragma unroll
            for (int rr = 0; rr < 4; rr++) {
                int tv = tt * 16 + kg * 4 + rr;
                if (tv < 50) {
                    int tl = tv >= 25 ? 1 : 0, u = tv - tl * 25;
                    int n0 = tl * 128 + ob + l15;
                    int n1 = n0 + 16;
                    Bt[n0 * 32 + (((u >> 3) ^ ((n0 >> 1) & 3)) << 3) + (u & 7)] = f2bf(h0[rr]);
                    Bt[n1 * 32 + (((u >> 3) ^ ((n1 >> 1) & 3)) << 3) + (u & 7)] = f2bf(h1[rr]);
                }
            }
        }
        __syncthreads();
        short8v aA[2];
#pragma unroll
        for (int mt = 0; mt < 2; mt++)
            aA[mt] = *(const short8v*)(An + (mt * 16 + l15) * 96 + s * 32 + kg * 8);
#pragma unroll
        for (int jj = 0; jj < 4; jj++) {
            int nr = (jb + jj) * 16 + l15;
            short8v b = *(const short8v*)&Bt[nr * 32 + ((kg ^ ((nr >> 1) & 3)) << 3)];
#pragma unroll
            for (int mt = 0; mt < 2; mt++)
                accS[mt][jj] = __builtin_amdgcn_mfma_f32_16x16x32_bf16(aA[mt], b, accS[mt][jj], 0, 0, 0);
        }
        __syncthreads();
    }
#pragma unroll
    for (int mt = 0; mt < 2; mt++)
#pragma unroll
        for (int jj = 0; jj < 4; jj++) {
            int nr = (jb + jj) * 16 + l15;
            int tl = nr >> 7, o = nr & 127;
            float sc = sc1[o], of = of1[o];
#pragma unroll
            for (int rr = 0; rr < 4; rr++) {
                int v = mt * 16 + kg * 4 + rr;
                if (v < 25) {
                    int tvl = tl * 25 + v;
                    float h = accS[mt][jj][rr] * sc + of + bf2f(xT[tvl * 136 + o]);
                    h = h > 0.f ? h : 0.1f * h;
                    y1T[tvl * 136 + o] = f2bf(h);
                }
            }
        }
    __syncthreads();
    short8v aF[2][4];
#pragma unroll
    for (int mt = 0; mt < 2; mt++)
#pragma unroll
        for (int k = 0; k < 4; k++)
            aF[mt][k] = *(const short8v*)&Wf[(ob + mt * 16 + l15) * 128 + k * 32 + kg * 8];
    float* on = outp + (size_t)n * 204800;
#pragma unroll
    for (int nt = 0; nt < 4; nt++) {
        short8v bY[4];
#pragma unroll
        for (int k = 0; k < 4; k++)
            bY[k] = *(short8v*)&y1T[(nt * 16 + l15) * 136 + k * 32 + kg * 8];
        f32x4 c0 = {0.f, 0.f, 0.f, 0.f}, c1 = {0.f, 0.f, 0.f, 0.f};
#pragma unroll
        for (int k = 0; k < 4; k++) {
            c0 = __builtin_amdgcn_mfma_f32_16x16x32_bf16(aF[0][k], bY[k], c0, 0, 0, 0);
            c1 = __builtin_amdgcn_mfma_f32_16x16x32_bf16(aF[1][k], bY[k], c1, 0, 0, 0);
        }
        int tv = nt * 16 + l15;
        if (tv < 50) {
#pragma unroll
            for (int rr = 0; rr < 4; rr++) {
                {
                    int o = ob + kg * 4 + rr;
                    float h = c0[rr] * sc2[o] + of2[o] + bf2f(xT[tv * 136 + o]);
                    on[(size_t)o * 1600 + tvg0 + tv] = h > 0.f ? h : 0.1f * h;
                }
                {
                    int o = ob + 16 + kg * 4 + rr;
                    float h = c1[rr] * sc2[o] + of2[o] + bf2f(xT[tv * 136 + o]);
                    on[(size_t)o * 1600 + tvg0 + tv] = h > 0.f ? h : 0.1f * h;
                }
            }
        }
    }
}

// ------- y_cvt: y_bf[n][tv][128c] bf16 = transpose of y fp32 [c][tv] -------
__global__ __launch_bounds__(256) void y_cvt(
    const float* __restrict__ y, ushort* __restrict__ y_bf)
{
    __shared__ __align__(16) ushort xT[160 * 136];
    const int np = blockIdx.y, tvb = blockIdx.x * 160;
    const float* sn = y + (size_t)np * 204800;
    for (int i = threadIdx.x; i < 2560; i += 256) {
        int tv4 = (i & 7) + (i >> 9) * 8;
        int cp  = (i >> 3) & 63;
        float4 a = *(const float4*)(sn + (2 * cp) * 1600 + tvb + tv4 * 4);
        float4 b = *(const float4*)(sn + (2 * cp + 1) * 1600 + tvb + tv4 * 4);
        float av[4] = { a.x, a.y, a.z, a.w };
        float bv[4] = { b.x, b.y, b.z, b.w };
#pragma unroll
        for (int e = 0; e < 4; e++) {
            uint p = (uint)f2bf(av[e]) | ((uint)f2bf(bv[e]) << 16);
            ((uint*)xT)[(tv4 * 4 + e) * 68 + cp] = p;
        }
    }
    __syncthreads();
    uint* dst = (uint*)(y_bf + (size_t)np * 204800 + (size_t)tvb * 128);
    for (int i = threadIdx.x; i < 10240; i += 256) {
        int tv = i >> 6, cp = i & 63;
        dst[tv * 64 + cp] = ((const uint*)xT)[tv * 68 + cp];
    }
}

// ------- tt_fused: temporal t1+t2+res per (n, v); y1 overwrites y_bf in place -------
// G[s,t,o] = sum_c Wo_t[s,o,c] * y[c,t,v] in LDS; y1[(q*25+v)][o] = lrelu(y + BN1(sum attT*G)).
__global__ __launch_bounds__(256) void tt_fused(
    ushort* __restrict__ ybuf /* y_bf in, y1 out (in place) */,
    const ushort* __restrict__ Wo /*[3][128o][128c]*/,
    const ushort* __restrict__ attT /*[n][64q][192]*/,
    const float* __restrict__ bnp, const float* __restrict__ bo)
{
    __shared__ __align__(16) ushort yS[64 * 136];   // [t][c]
    __shared__ __align__(16) ushort Gl[128 * 72];   // [o][64 t + 8 pad]
    __shared__ float sc_l[128], of_l[128];
    const int v = blockIdx.x, np = blockIdx.y;
    if (threadIdx.x < 128) {
        int o = threadIdx.x;
        float sc = bnp[o] * rsqrtf(bnp[384 + o] + 1e-5f);
        sc_l[o] = sc;
        of_l[o] = (bo[o] - bnp[256 + o]) * sc + bnp[128 + o];
    }
    ushort* yq = ybuf + (size_t)np * 204800;
    // stage y slice coalesced: yS[t][c] = y_bf[(t*25+v)*128 + c]  (64 rows x 256 B)
    for (int i = threadIdx.x; i < 4096; i += 256) {
        int t = i >> 6, cp = i & 63;
        ((uint*)yS)[t * 68 + cp] = *(const uint*)(yq + (size_t)(t * 25 + v) * 128 + cp * 2);
    }
    __syncthreads();
    const int lane = threadIdx.x & 63, wave = threadIdx.x >> 6;
    const int l15 = lane & 15, kg = lane >> 4;
    const int ob = wave * 32;
    const ushort* An = attT + (size_t)np * 12288;
    f32x4 acc[4][2];
#pragma unroll
    for (int mt = 0; mt < 4; mt++)
#pragma unroll
        for (int jj = 0; jj < 2; jj++) acc[mt][jj] = (f32x4){0.f, 0.f, 0.f, 0.f};
    for (int s = 0; s < 3; s++) {
        short8v bW[2][4];
#pragma unroll
        for (int nt = 0; nt < 2; nt++)
#pragma unroll
            for (int k = 0; k < 4; k++)
                bW[nt][k] = *(const short8v*)&Wo[s * 16384 +
                             (ob + nt * 16 + l15) * 128 + k * 32 + kg * 8];
#pragma unroll
        for (int mt = 0; mt < 4; mt++) {
            short8v aX[4];
#pragma unroll
            for (int k = 0; k < 4; k++)
                aX[k] = *(short8v*)&yS[(mt * 16 + l15) * 136 + k * 32 + kg * 8];
            f32x4 g0 = {0.f, 0.f, 0.f, 0.f}, g1 = {0.f, 0.f, 0.f, 0.f};
#pragma unroll
            for (int k = 0; k < 4; k++) {
                g0 = __builtin_amdgcn_mfma_f32_16x16x32_bf16(aX[k], bW[0][k], g0, 0, 0, 0);
                g1 = __builtin_amdgcn_mfma_f32_16x16x32_bf16(aX[k], bW[1][k], g1, 0, 0, 0);
            }
#pragma unroll
            for (int rr = 0; rr < 4; rr++) {
                int t = mt * 16 + kg * 4 + rr;
                Gl[(ob + l15) * 72 + t]      = f2bf(g0[rr]);
                Gl[(ob + 16 + l15) * 72 + t] = f2bf(g1[rr]);
            }
        }
        __syncthreads();
#pragma unroll
        for (int ks = 0; ks < 2; ks++) {
            short8v b2[2];
#pragma unroll
            for (int jj = 0; jj < 2; jj++)
                b2[jj] = *(short8v*)&Gl[(ob + jj * 16 + l15) * 72 + ks * 32 + kg * 8];
#pragma unroll
            for (int mt = 0; mt < 4; mt++) {
                short8v a2 = *(const short8v*)(An + (mt * 16 + l15) * 192 + s * 64 + ks * 32 + kg * 8);
#pragma unroll
                for (int jj = 0; jj < 2; jj++)
                    acc[mt][jj] = __builtin_amdgcn_mfma_f32_16x16x32_bf16(a2, b2[jj], acc[mt][jj], 0, 0, 0);
            }
        }
        __syncthreads();
    }
    // y1 = lrelu(y + BN1(acc)); residual y[o][q*25+v] = yS[q][o]; write in place
#pragma unroll
    for (int mt = 0; mt < 4; mt++)
#pragma unroll
        for (int jj = 0; jj < 2; jj++) {
            int o = ob + jj * 16 + l15;
            float sc = sc_l[o], of = of_l[o];
#pragma unroll
            for (int rr = 0; rr < 4; rr++) {
                int q = mt * 16 + kg * 4 + rr;
                float h = acc[mt][jj][rr] * sc + of + bf2f(yS[q * 136 + o]);
                h = h > 0.f ? h : 0.1f * h;
                yq[(size_t)(q * 25 + v) * 128 + o] = f2bf(h);
            }
        }
}

// ------- cbr (MFMA, temporal): out = lrelu(res + BN2(Wf @ y1 + b)) -------
__global__ __launch_bounds__(256) void cbr_mfma(
    const ushort* __restrict__ y1 /*[n][tv][128c] bf16*/, const float* res,
    const ushort* __restrict__ Wbf, const float* __restrict__ bias,
    const float* __restrict__ bnp, float* outp)
{
    __shared__ __align__(16) ushort xT[160 * 136];
    __shared__ float sc_l[128], of_l[128];
    const int np = blockIdx.y, tvb = blockIdx.x * 160;
    if (threadIdx.x < 128) {
        int o = threadIdx.x;
        float sc = bnp[o] * rsqrtf(bnp[384 + o] + 1e-5f);
        sc_l[o] = sc;
        of_l[o] = (bias[o] - bnp[256 + o]) * sc + bnp[128 + o];
    }
    const ushort* pp = y1 + (size_t)np * 204800 + (size_t)tvb * 128;
    for (int i = threadIdx.x; i < 10240; i += 256) {
        int tl = i >> 6, cp = i & 63;
        ((uint*)xT)[tl * 68 + cp] = *(const uint*)(pp + tl * 128 + cp * 2);
    }
    __syncthreads();
    const int lane = threadIdx.x & 63, wave = threadIdx.x >> 6;
    const int l15 = lane & 15, kg = lane >> 4;
    const int ob = wave * 32;
    short8v af[2][4];
#pragma unroll
    for (int mt = 0; mt < 2; mt++)
#pragma unroll
        for (int k = 0; k < 4; k++)
            af[mt][k] = *(const short8v*)&Wbf[(ob + mt * 16 + l15) * 128 + k * 32 + kg * 8];
    const float* res_n = res + (size_t)np * 204800;
    float* out_n = outp + (size_t)np * 204800;
    for (int nt = 0; nt < 10; nt++) {
        short8v bfg[4];
#pragma unroll
        for (int k = 0; k < 4; k++)
            bfg[k] = *(short8v*)&xT[(nt * 16 + l15) * 136 + k * 32 + kg * 8];
        f32x4 acc0 = {0.f, 0.f, 0.f, 0.f};
        f32x4 acc1 = {0.f, 0.f, 0.f, 0.f};
#pragma unroll
        for (int k = 0; k < 4; k++) {
            acc0 = __builtin_amdgcn_mfma_f32_16x16x32_bf16(af[0][k], bfg[k], acc0, 0, 0, 0);
            acc1 = __builtin_amdgcn_mfma_f32_16x16x32_bf16(af[1][k], bfg[k], acc1, 0, 0, 0);
        }
        int tv = tvb + nt * 16 + l15;
#pragma unroll
        for (int rr = 0; rr < 4; rr++) {
            {
                int o = ob + kg * 4 + rr;
                size_t idx = (size_t)o * 1600 + tv;
                float h = acc0[rr] * sc_l[o] + of_l[o] + res_n[idx];
                out_n[idx] = h > 0.f ? h : 0.1f * h;
            }
            {
                int o = ob + 16 + kg * 4 + rr;
                size_t idx = (size_t)o * 1600 + tv;
                float h = acc1[rr] * sc_l[o] + of_l[o] + res_n[idx];
                out_n[idx] = h > 0.f ? h : 0.1f * h;
            }
        }
    }
}

extern "C" void kernel_launch(void* const* d_in, const int* in_sizes, int n_in,
                              void* d_out, int out_size, void* d_ws, size_t ws_size,
                              hipStream_t stream)
{
    (void)in_sizes; (void)n_in; (void)out_size; (void)ws_size;
    const float* x      = (const float*)d_in[0];
    const float* Wqk_s  = (const float*)d_in[1];
    const float* bqk_s  = (const float*)d_in[2];
    const float* alphas = (const float*)d_in[3];
    const float* att0s  = (const float*)d_in[4];
    const float* Wo_s   = (const float*)d_in[5];
    const float* bo_s   = (const float*)d_in[6];
    const float* bn_o_s = (const float*)d_in[7];
    const float* Wf_s   = (const float*)d_in[8];
    const float* bf_s   = (const float*)d_in[9];
    const float* bn_f_s = (const float*)d_in[10];
    const float* Wqk_t  = (const float*)d_in[11];
    const float* bqk_t  = (const float*)d_in[12];
    const float* alphat = (const float*)d_in[13];
    const float* att0t  = (const float*)d_in[14];
    const float* Wo_t   = (const float*)d_in[15];
    const float* bo_t   = (const float*)d_in[16];
    const float* bn_o_t = (const float*)d_in[17];
    const float* Wf_t   = (const float*)d_in[18];
    const float* bf_t   = (const float*)d_in[19];
    const float* bn_f_t = (const float*)d_in[20];

    float* out = (float*)d_out;
    // ws layout (bytes):
    //  [0, 78,643,200)   qk bf16 [n][192][1600]; y_bf/y1 [n][1600][128] bf16 (52.4 MB)
    //                    overlays this region AFTER att_t consumed qk.
    //  [78,643,200, 79,429,632)  attS_bf
    //  [79,603,200, 82,748,928)  attT_bf
    //  [85,894,656, +360,448)    W16 bf16 weights
    ushort* qk      = (ushort*)d_ws;
    ushort* ybuf    = (ushort*)d_ws;
    ushort* attS_bf = (ushort*)((char*)d_ws + 78643200);
    ushort* attT_bf = (ushort*)((char*)d_ws + 79603200);
    ushort* W16     = (ushort*)((char*)d_ws + 85894656);
    const ushort* WoS_bf  = W16;
    const ushort* WfS_bf  = W16 + 49152;
    const ushort* WoT_bf  = W16 + 65536;
    const ushort* WfT_bf  = W16 + 114688;
    const ushort* WqkS_bf = W16 + 131072;
    const ushort* WqkT_bf = W16 + 155648;

    wt_prep<<<704, 256, 0, stream>>>(Wo_s, Wf_s, Wo_t, Wf_t, Wqk_s, Wqk_t, W16);

    dim3 gqk(10, 128), gatt(3, 128), gsf(32, 128), gyc(10, 128), gtt(25, 128), gcbr(10, 128);

    // ---- spatial ----
    qk_pe_mfma<<<gqk, 256, 0, stream>>>(x, WqkS_bf, bqk_s, qk, 0);
    att_s_mfma<<<gatt, 256, 0, stream>>>(qk, alphas, att0s, attS_bf);
    s_fused<<<gsf, 256, 0, stream>>>(x, WoS_bf, attS_bf, WfS_bf,
                                     bn_o_s, bo_s, bn_f_s, bf_s, out);

    // ---- temporal ----
    qk_pe_mfma<<<gqk, 256, 0, stream>>>(out, WqkT_bf, bqk_t, qk, 1);
    att_t_mfma<<<gatt, 256, 0, stream>>>(qk, alphat, att0t, attT_bf);
    y_cvt<<<gyc, 256, 0, stream>>>(out, ybuf);            // qk dead now; ybuf overlays it
    tt_fused<<<gtt, 256, 0, stream>>>(ybuf, WoT_bf, attT_bf, bn_o_t, bo_t);
    cbr_mfma<<<gcbr, 256, 0, stream>>>(ybuf, out, WfT_bf, bf_t, bn_f_t, out);
}